// Round 13
// baseline (295.276 us; speedup 1.0000x reference)
//
#include <hip/hip_runtime.h>

// ---- types / helpers -------------------------------------------------------
typedef __bf16 bf16x8 __attribute__((ext_vector_type(8)));
typedef __bf16 bf16x4 __attribute__((ext_vector_type(4)));
typedef __bf16 bf16x2 __attribute__((ext_vector_type(2)));
typedef float f32x4 __attribute__((ext_vector_type(4)));
typedef float f32x16 __attribute__((ext_vector_type(16)));
typedef unsigned short ushortx8 __attribute__((ext_vector_type(8)));
typedef unsigned short ushortx4 __attribute__((ext_vector_type(4)));
typedef unsigned int uint32x4v __attribute__((ext_vector_type(4)));

#define DEVI static __device__ __forceinline__

DEVI unsigned short f2bf(float f) {  // round-to-nearest-even f32 -> bf16
  unsigned int u = __builtin_bit_cast(unsigned int, f);
  u += 0x7FFFu + ((u >> 16) & 1u);
  return (unsigned short)(u >> 16);
}

DEVI bf16x8 ld8(const unsigned short* p) {  // 16B vector load (global or LDS)
  return __builtin_bit_cast(bf16x8, *(const ushortx8*)p);
}

DEVI void gll16(const unsigned short* g, unsigned short* l) {  // global->LDS 16B DMA
  __builtin_amdgcn_global_load_lds((const __attribute__((address_space(1))) void*)g,
                                   (__attribute__((address_space(3))) void*)l, 16, 0, 0);
}

#define MFMA16(a, b, c) __builtin_amdgcn_mfma_f32_16x16x32_bf16(a, b, c, 0, 0, 0)
#define MFMA32(a, b, c) __builtin_amdgcn_mfma_f32_32x32x16_bf16(a, b, c, 0, 0, 0)

DEVI unsigned pkbf(float lo, float hi) {  // pack 2 f32 -> u32 of 2 bf16 (lo in low16)
  bf16x2 v;
  v[0] = (__bf16)lo;
  v[1] = (__bf16)hi;
  return __builtin_bit_cast(unsigned, v);
}

DEVI float swaphalf_max(float x) {  // max(own, other-32-lane-half) for all lanes
  unsigned xu = __builtin_bit_cast(unsigned, x);
  auto pr = __builtin_amdgcn_permlane32_swap(xu, xu, false, false);
  return fmaxf(__builtin_bit_cast(float, (unsigned)pr[0]),
               __builtin_bit_cast(float, (unsigned)pr[1]));
}

DEVI float swaphalf_add(float x) {
  unsigned xu = __builtin_bit_cast(unsigned, x);
  auto pr = __builtin_amdgcn_permlane32_swap(xu, xu, false, false);
  return __builtin_bit_cast(float, (unsigned)pr[0]) +
         __builtin_bit_cast(float, (unsigned)pr[1]);
}

// XOR-swizzled LDS read for 64-short (128 B) rows: byte ^= (row&7)<<4.
// Verified R7/R9: SQ_LDS_BANK_CONFLICT == 0 with the matching pre-swizzled src.
DEVI bf16x8 ldswz(const unsigned short* L, int row, int colsh) {
  return ld8(L + row * 64 + ((((colsh * 2) ^ ((row & 7) << 4))) >> 1));
}

// ---- problem constants -----------------------------------------------------
// B=4, T=2048, E=1024, H=16, D=64
#define SB 4
#define ST 2048
#define SE 1024
#define SH 16
#define SD 64
#define QSCALE 0.18033688011112042f  /* 0.125 * log2(e): Q pre-scale for exp2 softmax */
#define DMTHR 11.541560327111708f    /* defer-max threshold: 8 * log2(e) */

#define NXq4   2097152  /* (4*2048*1024)/4 */
#define NQKVq4  786432  /* (3*1024*1024)/4 */
#define NWOq4   262144  /* (1024*1024)/4 */

// ---- fused f32 -> bf16 convert (all three inputs, one launch) --------------
__global__ void cvt_all(const float* __restrict__ x, const float* __restrict__ wq,
                        const float* __restrict__ wo,
                        unsigned short* __restrict__ xb, unsigned short* __restrict__ wqb,
                        unsigned short* __restrict__ wob) {
  int i = blockIdx.x * blockDim.x + threadIdx.x;
  const float* src;
  unsigned short* dst;
  int j;
  if (i < NXq4) { src = x; dst = xb; j = i; }
  else if (i < NXq4 + NQKVq4) { src = wq; dst = wqb; j = i - NXq4; }
  else { src = wo; dst = wob; j = i - NXq4 - NQKVq4; }
  float4 v = ((const float4*)src)[j];
  ushortx4 o;
  o.x = f2bf(v.x); o.y = f2bf(v.y); o.z = f2bf(v.z); o.w = f2bf(v.w);
  ((ushortx4*)dst)[j] = o;
}

// ---- NT GEMM1: 256x256 tile, m201-style 4-phase/tile, counted vmcnt --------
// 512 thr = 8 waves (2M x 4N), per-wave 128x64 (8m x 4n frags). Per K-tile
// (BK=64): 4 phases, each = {ds_read A-quadrant (4 b128; P0 also reads all B:
// +8) || stage 1-3 chunks of a FUTURE tile into read-dead LDS regions ||
// s_barrier || lgkmcnt(0) || 16 MFMA (2m x 4n x 2ks) || s_barrier}. B frags
// live in registers across the tile, so B's LDS rows die after P0 -> WAR-safe
// staging targets inside the CURRENT buffer; A rows die quadrant by quadrant.
// Stage rotation for tile u+2: {P1: B r0,r1}, {P2: B r2,r3 + A r0}, {P3: A r2},
// {u+1.P0: A r1, A r3}. Boundary: vmcnt(6) (u+2's 6 chunks stay in flight --
// NEVER 0 mid-loop; m201's exact constant). 128 KB LDS, 1 block/CU.
// Epilogue scatters qkv -> Q (xQSCALE), K, VT bf16 (VT packed 8B stores).
__global__ __launch_bounds__(512, 2) void gemm_big1(
    const unsigned short* __restrict__ A, const unsigned short* __restrict__ Bw,
    unsigned short* __restrict__ Qo, unsigned short* __restrict__ Ko,
    unsigned short* __restrict__ VTo,
    int M, int N, int K) {
  __shared__ unsigned short As[2][256 * 64];  // 64 KB
  __shared__ unsigned short Bs[2][256 * 64];  // 64 KB
  const int tid = threadIdx.x;
  const int lane = tid & 63;
  const int w = tid >> 6;            // 0..7
  const int wr = w >> 2, wc = w & 3; // 2M x 4N
  const int r16 = lane & 15, g = lane >> 4;

  // XCD-aware remap: contiguous chunk per XCD (nwg=384, %8==0, bijective)
  const int nwg = gridDim.x * gridDim.y;
  const int lin = blockIdx.x + blockIdx.y * gridDim.x;
  const int wg = (lin & 7) * (nwg >> 3) + (lin >> 3);
  const int bx = wg % gridDim.x, by = wg / gridDim.x;
  const int m0 = by * 256, n0 = bx * 256;

  f32x4 acc[8][4] = {};

  // stage round r (64 rows) of tile v's A/B into buf v&1, src pre-swizzled
  auto stgA = [&](int v, int r) {
    int c = r * 512 + tid, row = c >> 3, j = c & 7;
    int src = ((j * 16) ^ ((row & 7) << 4)) >> 1;
    gll16(A + (size_t)(m0 + row) * K + (v << 6) + src, As[v & 1] + c * 8);
  };
  auto stgB = [&](int v, int r) {
    int c = r * 512 + tid, row = c >> 3, j = c & 7;
    int src = ((j * 16) ^ ((row & 7) << 4)) >> 1;
    gll16(Bw + (size_t)(n0 + row) * K + (v << 6) + src, Bs[v & 1] + c * 8);
  };

  const int ntk = K >> 6;  // 16
  // prologue: tile0 full (8) + tile1 partial {B r0-3, A r0, A r2} (6)
#pragma unroll
  for (int r = 0; r < 4; ++r) stgA(0, r);
#pragma unroll
  for (int r = 0; r < 4; ++r) stgB(0, r);
#pragma unroll
  for (int r = 0; r < 4; ++r) stgB(1, r);
  stgA(1, 0); stgA(1, 2);
  asm volatile("s_waitcnt vmcnt(6)" ::: "memory");  // tile0's 8 landed
  __builtin_amdgcn_s_barrier();
  __builtin_amdgcn_sched_barrier(0);

  for (int u = 0; u < ntk; ++u) {
    const unsigned short* Ab = As[u & 1];
    const unsigned short* Bb = Bs[u & 1];
    bf16x8 bfr[4][2], aq[2][2];

    // ---- P0: A-quad0 + ALL B; stage u+1's A r1,r3 (into other buf) ----
#pragma unroll
    for (int mt = 0; mt < 2; ++mt)
#pragma unroll
      for (int ks = 0; ks < 2; ++ks)
        aq[mt][ks] = ldswz(Ab, wr * 128 + mt * 16 + r16, ks * 32 + g * 8);
#pragma unroll
    for (int n = 0; n < 4; ++n)
#pragma unroll
      for (int ks = 0; ks < 2; ++ks)
        bfr[n][ks] = ldswz(Bb, wc * 64 + n * 16 + r16, ks * 32 + g * 8);
    if (u + 1 < ntk) { stgA(u + 1, 1); stgA(u + 1, 3); }
    asm volatile("s_waitcnt lgkmcnt(8)" ::: "memory");
    __builtin_amdgcn_s_barrier();
    asm volatile("s_waitcnt lgkmcnt(0)" ::: "memory");
    __builtin_amdgcn_sched_barrier(0);
    __builtin_amdgcn_s_setprio(1);
#pragma unroll
    for (int mt = 0; mt < 2; ++mt)
#pragma unroll
      for (int n = 0; n < 4; ++n)
#pragma unroll
        for (int ks = 0; ks < 2; ++ks)
          acc[mt][n] = MFMA16(aq[mt][ks], bfr[n][ks], acc[mt][n]);
    __builtin_amdgcn_s_setprio(0);
    __builtin_amdgcn_s_barrier();

    // ---- P1: A-quad1; stage u+2's B r0,r1 (B LDS dead after P0) ----
#pragma unroll
    for (int mt = 0; mt < 2; ++mt)
#pragma unroll
      for (int ks = 0; ks < 2; ++ks)
        aq[mt][ks] = ldswz(Ab, wr * 128 + 32 + mt * 16 + r16, ks * 32 + g * 8);
    if (u + 2 < ntk) { stgB(u + 2, 0); stgB(u + 2, 1); }
    __builtin_amdgcn_s_barrier();
    asm volatile("s_waitcnt lgkmcnt(0)" ::: "memory");
    __builtin_amdgcn_sched_barrier(0);
    __builtin_amdgcn_s_setprio(1);
#pragma unroll
    for (int mt = 0; mt < 2; ++mt)
#pragma unroll
      for (int n = 0; n < 4; ++n)
#pragma unroll
        for (int ks = 0; ks < 2; ++ks)
          acc[2 + mt][n] = MFMA16(aq[mt][ks], bfr[n][ks], acc[2 + mt][n]);
    __builtin_amdgcn_s_setprio(0);
    __builtin_amdgcn_s_barrier();

    // ---- P2: A-quad2; stage u+2's B r2,r3 + A r0 (rows 0-63 dead) ----
#pragma unroll
    for (int mt = 0; mt < 2; ++mt)
#pragma unroll
      for (int ks = 0; ks < 2; ++ks)
        aq[mt][ks] = ldswz(Ab, wr * 128 + 64 + mt * 16 + r16, ks * 32 + g * 8);
    if (u + 2 < ntk) { stgB(u + 2, 2); stgB(u + 2, 3); stgA(u + 2, 0); }
    __builtin_amdgcn_s_barrier();
    asm volatile("s_waitcnt lgkmcnt(0)" ::: "memory");
    __builtin_amdgcn_sched_barrier(0);
    __builtin_amdgcn_s_setprio(1);
#pragma unroll
    for (int mt = 0; mt < 2; ++mt)
#pragma unroll
      for (int n = 0; n < 4; ++n)
#pragma unroll
        for (int ks = 0; ks < 2; ++ks)
          acc[4 + mt][n] = MFMA16(aq[mt][ks], bfr[n][ks], acc[4 + mt][n]);
    __builtin_amdgcn_s_setprio(0);
    __builtin_amdgcn_s_barrier();

    // ---- P3: A-quad3; stage u+2's A r2 (rows 128-191 dead) ----
#pragma unroll
    for (int mt = 0; mt < 2; ++mt)
#pragma unroll
      for (int ks = 0; ks < 2; ++ks)
        aq[mt][ks] = ldswz(Ab, wr * 128 + 96 + mt * 16 + r16, ks * 32 + g * 8);
    if (u + 2 < ntk) stgA(u + 2, 2);
    __builtin_amdgcn_s_barrier();
    asm volatile("s_waitcnt lgkmcnt(0)" ::: "memory");
    __builtin_amdgcn_sched_barrier(0);
    __builtin_amdgcn_s_setprio(1);
#pragma unroll
    for (int mt = 0; mt < 2; ++mt)
#pragma unroll
      for (int n = 0; n < 4; ++n)
#pragma unroll
        for (int ks = 0; ks < 2; ++ks)
          acc[6 + mt][n] = MFMA16(aq[mt][ks], bfr[n][ks], acc[6 + mt][n]);
    __builtin_amdgcn_s_setprio(0);

    // tile boundary: u+1 fully resident; u+2's 6 chunks stay in flight
    if (u + 1 < ntk) {
      if (u + 2 < ntk) asm volatile("s_waitcnt vmcnt(6)" ::: "memory");
      else             asm volatile("s_waitcnt vmcnt(0)" ::: "memory");
    }
    __builtin_amdgcn_s_barrier();
    __builtin_amdgcn_sched_barrier(0);
  }

  // epilogue: per-frag C layout col = lane&15, row = (lane>>4)*4 + r
  const int which = (n0 + wc * 64) >> 10;  // wave-uniform (256|1024 aligned)
#pragma unroll
  for (int mt = 0; mt < 8; ++mt) {
    const int tb = m0 + wr * 128 + mt * 16 + g * 4;  // 4 consecutive m (=t)
    const int b = tb >> 11, t = tb & (ST - 1);
#pragma unroll
    for (int nt2 = 0; nt2 < 4; ++nt2) {
      int n = n0 + wc * 64 + nt2 * 16 + r16;
      int h = (n >> 6) & (SH - 1), d = n & (SD - 1);
      int bh = b * SH + h;
      if (which == 2) {  // VT[bh][d][t]: 4 consecutive t -> one 8B store
        ushortx4 o;
#pragma unroll
        for (int r = 0; r < 4; ++r) o[r] = f2bf(acc[mt][nt2][r]);
        *(ushortx4*)&VTo[((size_t)bh * SD + d) * ST + t] = o;
      } else if (which == 0) {
#pragma unroll
        for (int r = 0; r < 4; ++r)
          Qo[((size_t)bh * ST + t + r) * SD + d] = f2bf(acc[mt][nt2][r] * QSCALE);
      } else {
#pragma unroll
        for (int r = 0; r < 4; ++r)
          Ko[((size_t)bh * ST + t + r) * SD + d] = f2bf(acc[mt][nt2][r]);
      }
    }
  }
}

// ---- NT GEMM small (R9-proven): 128x128, single-buffer, 256 thr ------------
// 2 blocks/CU, swizzled (0 conflicts). Used for GEMM2 (M=8192,N=1024,K=1024).
__global__ __launch_bounds__(256, 2) void gemm_sm(
    const unsigned short* __restrict__ A, const unsigned short* __restrict__ Bw,
    float* __restrict__ Cf, int M, int N, int K) {
  __shared__ unsigned short As[128 * 64];
  __shared__ unsigned short Bs[128 * 64];
  const int tid = threadIdx.x;
  const int lane = tid & 63;
  const int w = tid >> 6;
  const int wr = w >> 1, wc = w & 1;
  const int r16 = lane & 15, g = lane >> 4;

  const int nwg = gridDim.x * gridDim.y;
  const int lin = blockIdx.x + blockIdx.y * gridDim.x;
  const int wg = (lin & 7) * (nwg >> 3) + (lin >> 3);
  const int bx = wg % gridDim.x, by = wg / gridDim.x;
  const int m0 = by * 128, n0 = bx * 128;

  f32x4 acc[4][4] = {};

  for (int k0 = 0; k0 < K; k0 += 64) {
    __syncthreads();
#pragma unroll
    for (int it = 0; it < 4; ++it) {
      int c = it * 256 + tid;
      int row = c >> 3, j = c & 7;
      int src = ((j * 16) ^ ((row & 7) << 4)) >> 1;
      gll16(A + (size_t)(m0 + row) * K + k0 + src, As + c * 8);
    }
#pragma unroll
    for (int it = 0; it < 4; ++it) {
      int c = it * 256 + tid;
      int row = c >> 3, j = c & 7;
      int src = ((j * 16) ^ ((row & 7) << 4)) >> 1;
      gll16(Bw + (size_t)(n0 + row) * K + k0 + src, Bs + c * 8);
    }
    __syncthreads();
#pragma unroll
    for (int ks = 0; ks < 2; ++ks) {
      bf16x8 af[4], bfr[4];
#pragma unroll
      for (int mt = 0; mt < 4; ++mt)
        af[mt] = ldswz(As, wr * 64 + mt * 16 + r16, ks * 32 + g * 8);
#pragma unroll
      for (int nt2 = 0; nt2 < 4; ++nt2)
        bfr[nt2] = ldswz(Bs, wc * 64 + nt2 * 16 + r16, ks * 32 + g * 8);
#pragma unroll
      for (int mt = 0; mt < 4; ++mt)
#pragma unroll
        for (int nt2 = 0; nt2 < 4; ++nt2)
          acc[mt][nt2] = MFMA16(af[mt], bfr[nt2], acc[mt][nt2]);
    }
  }

#pragma unroll
  for (int mt = 0; mt < 4; ++mt)
#pragma unroll
    for (int nt2 = 0; nt2 < 4; ++nt2)
#pragma unroll
      for (int r = 0; r < 4; ++r) {
        int m = m0 + wr * 64 + mt * 16 + g * 4 + r;
        int n = n0 + wc * 64 + nt2 * 16 + r16;
        Cf[(size_t)m * N + n] = acc[mt][nt2][r];
      }
}

// ---- causal flash attention v7 (= v6 + seeded-accumulator exp2) ------------
// QBLK=128 (4 waves x 32 q-cols), KVBLK=64, double-buffered K/V, XOR swizzle.
// 32x32x16 MFMA, swapped operands. Softmax in-register (permlane32_swap T12).
// SEEDED QK accumulator: s init = -mrow, so the common defer-max path calls
// exp2 with NO subtract (R5's numerically-proven subset; its spill came from
// ls_acc/onesf which are NOT reintroduced). mrow starts at 0 (safe: scale
// cancels; first-tile scores are ~N(0,1.4) << DMTHR). XCD-affinity remap.
DEVI void stage_tile(const unsigned short* gbase, size_t rowstride,
                     unsigned short* lds, int tid) {
#pragma unroll
  for (int it = 0; it < 2; ++it) {
    int c = it * 256 + tid;
    int row = c >> 3, j = c & 7;
    int src = ((j * 16) ^ ((row & 7) << 4)) >> 1;  // shorts
    gll16(gbase + (size_t)row * rowstride + src, lds + c * 8);
  }
}

__global__ __launch_bounds__(256, 4) void attn_causal(
    const unsigned short* __restrict__ Q, const unsigned short* __restrict__ Kv,
    const unsigned short* __restrict__ VT, unsigned short* __restrict__ Y) {
  __shared__ unsigned short Ks[2][64 * 64];   // [t][d], swizzled
  __shared__ unsigned short Vs[2][64 * 64];   // [d][t], swizzled

  const int tid = threadIdx.x;
  const int lane = tid & 63;
  const int w = tid >> 6;
  const int l5 = lane & 31, h = lane >> 5;

  // XCD-affinity remap: xcd = lin&7 handles heads {xcd, xcd+8, ...};
  // qt descending -> all 64 heads' heaviest blocks dispatch first.
  const int lin = blockIdx.x + blockIdx.y * gridDim.x;  // 0..1023
  const int xcd = lin & 7;
  const int idx = lin >> 3;                 // 0..127
  const int qt = (ST / 128 - 1) - (idx >> 3);
  const int bh = xcd + 8 * (idx & 7);
  const size_t base = (size_t)bh * ST * SD;

  const int q_glob = qt * 128 + w * 32 + l5;   // this lane's q-row
  const int qwmin = qt * 128 + w * 32;         // wave q range [qwmin, qwmin+31]

  // Q B-fragments: col n = q = lane&31, k = h*8 + i, chained over kk (d-slices)
  bf16x8 qf[4];
#pragma unroll
  for (int kk = 0; kk < 4; ++kk)
    qf[kk] = ld8(Q + base + (size_t)q_glob * SD + kk * 16 + h * 8);

  float mrow = 0.f;   // running max in exp2 domain; 0-init safe (scale cancels)
  float lrow = 0.f;
  f32x16 acc[2] = {};  // O^T: lane q=l5, d = dblk*32 + (reg&3) + 4h + 8*(reg>>2)

  const int nkv = 2 * qt + 2;
  stage_tile(Kv + base, SD, Ks[0], tid);
  stage_tile(VT + base, ST, Vs[0], tid);
  __syncthreads();

  for (int kvt = 0; kvt < nkv; ++kvt) {
    const int cur = kvt & 1;
    if (kvt + 1 < nkv) {  // prefetch next tile into other buffer
      stage_tile(Kv + base + (size_t)(kvt + 1) * 64 * SD, SD, Ks[cur ^ 1], tid);
      stage_tile(VT + base + (kvt + 1) * 64, ST, Vs[cur ^ 1], tid);
    }

    // tiles fully above this wave's q range contribute nothing
    const bool active = (kvt * 64) <= (qwmin + 31);
    if (active) {
      // S' = K Q^T - mrow (accumulator seeded): lane owns q=l5, t-half per h
      f32x16 s0, s1;
      const float negm = -mrow;
#pragma unroll
      for (int i = 0; i < 16; ++i) { s0[i] = negm; s1[i] = negm; }
      __builtin_amdgcn_s_setprio(1);
#pragma unroll
      for (int kk = 0; kk < 4; ++kk) {
        bf16x8 k0 = ldswz(Ks[cur], l5, kk * 16 + h * 8);
        s0 = MFMA32(k0, qf[kk], s0);
      }
#pragma unroll
      for (int kk = 0; kk < 4; ++kk) {
        bf16x8 k1 = ldswz(Ks[cur], 32 + l5, kk * 16 + h * 8);
        s1 = MFMA32(k1, qf[kk], s1);
      }
      __builtin_amdgcn_s_setprio(0);

      if (kvt * 64 + 63 > qwmin) {  // diagonal overlap: causal mask
        const int t0 = kvt * 64 + 4 * h;
#pragma unroll
        for (int reg = 0; reg < 16; ++reg) {
          int t = t0 + (reg & 3) + 8 * (reg >> 2);
          if (t > q_glob) s0[reg] = -__builtin_inff();
          if (t + 32 > q_glob) s1[reg] = -__builtin_inff();
        }
      }

      // row max (relative to mrow): in-lane tree + one half-swap
      f32x16 mx;
#pragma unroll
      for (int i = 0; i < 16; ++i) mx[i] = fmaxf(s0[i], s1[i]);
#pragma unroll
      for (int i = 0; i < 8; ++i) mx[i] = fmaxf(mx[i], mx[i + 8]);
#pragma unroll
      for (int i = 0; i < 4; ++i) mx[i] = fmaxf(mx[i], mx[i + 4]);
      float bm = fmaxf(fmaxf(mx[0], mx[1]), fmaxf(mx[2], mx[3]));
      bm = swaphalf_max(bm);

      if (__any(bm > DMTHR)) {  // rare: rescale path (subtract here only)
        float delta = fmaxf(bm, 0.f);
        float corr = exp2f(-delta);
        mrow += delta;
        lrow *= corr;
#pragma unroll
        for (int dblk = 0; dblk < 2; ++dblk)
#pragma unroll
          for (int i = 0; i < 16; ++i) acc[dblk][i] *= corr;
#pragma unroll
        for (int i = 0; i < 16; ++i) {
          s0[i] = exp2f(s0[i] - delta);
          s1[i] = exp2f(s1[i] - delta);
        }
      } else {  // common: exp2 directly, zero subtracts
#pragma unroll
        for (int i = 0; i < 16; ++i) {
          s0[i] = exp2f(s0[i]);
          s1[i] = exp2f(s1[i]);
        }
      }

      // row sum: in-lane tree + half-swap
      f32x16 sm;
#pragma unroll
      for (int i = 0; i < 16; ++i) sm[i] = s0[i] + s1[i];
#pragma unroll
      for (int i = 0; i < 8; ++i) sm[i] += sm[i + 8];
#pragma unroll
      for (int i = 0; i < 4; ++i) sm[i] += sm[i + 4];
      float rs = (sm[0] + sm[1]) + (sm[2] + sm[3]);
      lrow += swaphalf_add(rs);

      // pack P -> bf16 PV B-fragments via permlane32_swap (no LDS roundtrip)
      bf16x8 pb[2][2];
      auto packblk = [&](const f32x16& S, bf16x8* out) {
        unsigned a = pkbf(S[0], S[1]), b2 = pkbf(S[2], S[3]);
        unsigned c = pkbf(S[4], S[5]), d2 = pkbf(S[6], S[7]);
        auto r0 = __builtin_amdgcn_permlane32_swap(a, c, false, false);
        auto r1 = __builtin_amdgcn_permlane32_swap(b2, d2, false, false);
        uint32x4v w0 = {(unsigned)r0[0], (unsigned)r1[0], (unsigned)r0[1], (unsigned)r1[1]};
        out[0] = __builtin_bit_cast(bf16x8, w0);
        unsigned e = pkbf(S[8], S[9]), f2 = pkbf(S[10], S[11]);
        unsigned g2 = pkbf(S[12], S[13]), h2 = pkbf(S[14], S[15]);
        auto r2 = __builtin_amdgcn_permlane32_swap(e, g2, false, false);
        auto r3 = __builtin_amdgcn_permlane32_swap(f2, h2, false, false);
        uint32x4v w1 = {(unsigned)r2[0], (unsigned)r3[0], (unsigned)r2[1], (unsigned)r3[1]};
        out[1] = __builtin_bit_cast(bf16x8, w1);
      };
      packblk(s0, pb[0]);
      packblk(s1, pb[1]);

      // O^T += V^T P^T : A = V^T (d rows), B = P^T (q cols)
      __builtin_amdgcn_s_setprio(1);
#pragma unroll
      for (int dblk = 0; dblk < 2; ++dblk)
#pragma unroll
        for (int tt = 0; tt < 2; ++tt)
#pragma unroll
          for (int sl = 0; sl < 2; ++sl) {
            bf16x8 va = ldswz(Vs[cur], dblk * 32 + l5, tt * 32 + sl * 16 + h * 8);
            acc[dblk] = MFMA32(va, pb[tt][sl], acc[dblk]);
          }
      __builtin_amdgcn_s_setprio(0);
    }

    __syncthreads();  // drains vmcnt (next tile staged) + guards buffer reuse
  }

  // epilogue: Y[B,T,E] bf16, e = head*64 + d; 4 consecutive d per reg-group
  const int b = bh >> 4, hd = bh & 15;
  const float inv = 1.f / lrow;
#pragma unroll
  for (int dblk = 0; dblk < 2; ++dblk)
#pragma unroll
    for (int rg = 0; rg < 4; ++rg) {
      bf16x4 o;
#pragma unroll
      for (int j = 0; j < 4; ++j) o[j] = (__bf16)(acc[dblk][rg * 4 + j] * inv);
      int d = dblk * 32 + rg * 8 + 4 * h;
      *(ushortx4*)&Y[((size_t)b * ST + q_glob) * SE + hd * SD + d] =
          __builtin_bit_cast(ushortx4, o);
    }
}

// ---- launch ----------------------------------------------------------------
extern "C" void kernel_launch(void* const* d_in, const int* in_sizes, int n_in,
                              void* d_out, int out_size, void* d_ws, size_t ws_size,
                              hipStream_t stream) {
  const float* x = (const float*)d_in[0];       // [4,2048,1024]
  const float* w_qkv = (const float*)d_in[1];   // [3072,1024]
  const float* w_out = (const float*)d_in[2];   // [1024,1024]
  float* out = (float*)d_out;                   // [4,2048,1024] f32

  const size_t NX = (size_t)SB * ST * SE;       // 8388608
  const size_t NQKV = (size_t)3 * SE * SE;      // 3145728
  const size_t NWO = (size_t)SE * SE;           // 1048576
  const size_t NHD = (size_t)SB * SH * ST * SD; // 8388608

  unsigned short* xb    = (unsigned short*)d_ws;        // 16MB, reused as Y later
  unsigned short* wqkvb = xb + NX;                      // 6MB
  unsigned short* woutb = wqkvb + NQKV;                 // 2MB
  unsigned short* q     = woutb + NWO;                  // 16MB
  unsigned short* k     = q + NHD;                      // 16MB
  unsigned short* vT    = k + NHD;                      // 16MB
  unsigned short* y     = xb;                           // alias (xb dead after GEMM1)

  const int ncvt = NXq4 + NQKVq4 + NWOq4;       // 3145728
  cvt_all<<<ncvt / 256, 256, 0, stream>>>(x, w_qkv, w_out, xb, wqkvb, woutb);

  // qkv = x @ w_qkv^T, scattered into Q/K/VT   (grid 12x32 = 384, %8==0)
  gemm_big1<<<dim3(3 * SE / 256, SB * ST / 256), 512, 0, stream>>>(
      xb, wqkvb, q, k, vT, SB * ST, 3 * SE, SE);

  attn_causal<<<dim3(ST / 128, SB * SH), 256, 0, stream>>>(q, k, vT, y);

  // out = y @ w_out^T (f32 out)   (R9-proven 128x128 kernel, 512 blocks)
  gemm_sm<<<dim3(SE / 128, SB * ST / 128), 256, 0, stream>>>(
      y, woutb, out, SB * ST, SE, SE);
}

// Round 14
// 186.352 us; speedup vs baseline: 1.5845x; 1.5845x over previous
//
#include <hip/hip_runtime.h>

// ---- types / helpers -------------------------------------------------------
typedef __bf16 bf16x8 __attribute__((ext_vector_type(8)));
typedef __bf16 bf16x4 __attribute__((ext_vector_type(4)));
typedef __bf16 bf16x2 __attribute__((ext_vector_type(2)));
typedef float f32x4 __attribute__((ext_vector_type(4)));
typedef float f32x16 __attribute__((ext_vector_type(16)));
typedef unsigned short ushortx8 __attribute__((ext_vector_type(8)));
typedef unsigned short ushortx4 __attribute__((ext_vector_type(4)));
typedef unsigned int uint32x4v __attribute__((ext_vector_type(4)));

#define DEVI static __device__ __forceinline__

DEVI unsigned short f2bf(float f) {  // round-to-nearest-even f32 -> bf16
  unsigned int u = __builtin_bit_cast(unsigned int, f);
  u += 0x7FFFu + ((u >> 16) & 1u);
  return (unsigned short)(u >> 16);
}

DEVI bf16x8 ld8(const unsigned short* p) {  // 16B vector load (global or LDS)
  return __builtin_bit_cast(bf16x8, *(const ushortx8*)p);
}

DEVI void gll16(const unsigned short* g, unsigned short* l) {  // global->LDS 16B DMA
  __builtin_amdgcn_global_load_lds((const __attribute__((address_space(1))) void*)g,
                                   (__attribute__((address_space(3))) void*)l, 16, 0, 0);
}

#define MFMA16(a, b, c) __builtin_amdgcn_mfma_f32_16x16x32_bf16(a, b, c, 0, 0, 0)
#define MFMA32(a, b, c) __builtin_amdgcn_mfma_f32_32x32x16_bf16(a, b, c, 0, 0, 0)

DEVI unsigned pkbf(float lo, float hi) {  // pack 2 f32 -> u32 of 2 bf16 (lo in low16)
  bf16x2 v;
  v[0] = (__bf16)lo;
  v[1] = (__bf16)hi;
  return __builtin_bit_cast(unsigned, v);
}

DEVI float swaphalf_max(float x) {  // max(own, other-32-lane-half) for all lanes
  unsigned xu = __builtin_bit_cast(unsigned, x);
  auto pr = __builtin_amdgcn_permlane32_swap(xu, xu, false, false);
  return fmaxf(__builtin_bit_cast(float, (unsigned)pr[0]),
               __builtin_bit_cast(float, (unsigned)pr[1]));
}

DEVI float swaphalf_add(float x) {
  unsigned xu = __builtin_bit_cast(unsigned, x);
  auto pr = __builtin_amdgcn_permlane32_swap(xu, xu, false, false);
  return __builtin_bit_cast(float, (unsigned)pr[0]) +
         __builtin_bit_cast(float, (unsigned)pr[1]);
}

// XOR-swizzled LDS read for 64-short (128 B) rows: byte ^= (row&7)<<4.
// Verified R7/R9: SQ_LDS_BANK_CONFLICT == 0 with the matching pre-swizzled src.
DEVI bf16x8 ldswz(const unsigned short* L, int row, int colsh) {
  return ld8(L + row * 64 + ((((colsh * 2) ^ ((row & 7) << 4))) >> 1));
}

// ---- problem constants -----------------------------------------------------
// B=4, T=2048, E=1024, H=16, D=64
#define SB 4
#define ST 2048
#define SE 1024
#define SH 16
#define SD 64
#define QSCALE 0.18033688011112042f  /* 0.125 * log2(e): Q pre-scale for exp2 softmax */
#define DMTHR 11.541560327111708f    /* defer-max threshold: 8 * log2(e) */

#define NXq4   2097152  /* (4*2048*1024)/4 */
#define NQKVq4  786432  /* (3*1024*1024)/4 */
#define NWOq4   262144  /* (1024*1024)/4 */

// ---- fused f32 -> bf16 convert (all three inputs, one launch) --------------
__global__ void cvt_all(const float* __restrict__ x, const float* __restrict__ wq,
                        const float* __restrict__ wo,
                        unsigned short* __restrict__ xb, unsigned short* __restrict__ wqb,
                        unsigned short* __restrict__ wob) {
  int i = blockIdx.x * blockDim.x + threadIdx.x;
  const float* src;
  unsigned short* dst;
  int j;
  if (i < NXq4) { src = x; dst = xb; j = i; }
  else if (i < NXq4 + NQKVq4) { src = wq; dst = wqb; j = i - NXq4; }
  else { src = wo; dst = wob; j = i - NXq4 - NQKVq4; }
  float4 v = ((const float4*)src)[j];
  ushortx4 o;
  o.x = f2bf(v.x); o.y = f2bf(v.y); o.z = f2bf(v.z); o.w = f2bf(v.w);
  ((ushortx4*)dst)[j] = o;
}

// ---- NT GEMM big: 256x256 tile, per-wave 128x64, counted-vmcnt dbuf --------
// R12-proven (~860 TF on GEMM1). Schedule (race-safe counted vmcnt, dbuf=2,
// depth-2 prefetch): read ALL 24 frags of tile t -> ks0 MFMAs -> lgkmcnt(0) +
// raw barrier (all waves done reading buf[cur]) -> stage tile t+2 INTO
// buf[cur] (WAR-safe) -> ks1 MFMAs -> vmcnt(8) [t+1 resident, t+2's 8 loads
// stay in flight -- never 0 mid-loop] -> barrier.
// 512 thr, 8 waves (2M x 4N), LDS 128 KB (1 block/CU), lb(512,2) => 256 VGPR.
// R13 post-mortem: the 4-phase variant was ~neutral; keep this simpler one.
// EPI==1: scatter qkv -> Q (xQSCALE), K, VT bf16 (VT packed 8B stores).
template<int EPI>
__global__ __launch_bounds__(512, 2) void gemm_big(
    const unsigned short* __restrict__ A, const unsigned short* __restrict__ Bw,
    float* __restrict__ Cf,
    unsigned short* __restrict__ Qo, unsigned short* __restrict__ Ko,
    unsigned short* __restrict__ VTo,
    int M, int N, int K) {
  __shared__ unsigned short As[2][256 * 64];  // 64 KB
  __shared__ unsigned short Bs[2][256 * 64];  // 64 KB
  const int tid = threadIdx.x;
  const int lane = tid & 63;
  const int w = tid >> 6;            // 0..7
  const int wr = w >> 2, wc = w & 3; // 2M x 4N
  const int r16 = lane & 15, g = lane >> 4;

  // XCD-aware remap: contiguous chunk per XCD (nwg=384, %8==0, bijective)
  const int nwg = gridDim.x * gridDim.y;
  const int lin = blockIdx.x + blockIdx.y * gridDim.x;
  const int wg = (lin & 7) * (nwg >> 3) + (lin >> 3);
  const int bx = wg % gridDim.x, by = wg / gridDim.x;
  const int m0 = by * 256, n0 = bx * 256;

  f32x4 acc[8][4] = {};

  // stage K-tile kt (256x64 A + 256x64 B), src pre-swizzled; 8 gll16/thread
  auto stage = [&](int kt, int buf) {
    const int k0 = kt << 6;
#pragma unroll
    for (int it = 0; it < 4; ++it) {
      int c = it * 512 + tid;          // 0..2047
      int row = c >> 3, j = c & 7;
      int src = ((j * 16) ^ ((row & 7) << 4)) >> 1;
      gll16(A + (size_t)(m0 + row) * K + k0 + src, As[buf] + c * 8);
    }
#pragma unroll
    for (int it = 0; it < 4; ++it) {
      int c = it * 512 + tid;
      int row = c >> 3, j = c & 7;
      int src = ((j * 16) ^ ((row & 7) << 4)) >> 1;
      gll16(Bw + (size_t)(n0 + row) * K + k0 + src, Bs[buf] + c * 8);
    }
  };

  const int ntk = K >> 6;  // 16
  stage(0, 0);
  stage(1, 1);
  asm volatile("s_waitcnt vmcnt(8)" ::: "memory");  // tile 0 resident
  __builtin_amdgcn_s_barrier();
  __builtin_amdgcn_sched_barrier(0);

  int cur = 0;
  for (int t = 0; t < ntk; ++t) {
    const unsigned short* Ab = As[cur];
    const unsigned short* Bb = Bs[cur];

    // read ALL fragments of this K-tile (24 x ds_read_b128)
    bf16x8 af[8][2], bfr[4][2];
#pragma unroll
    for (int m = 0; m < 8; ++m)
#pragma unroll
      for (int ks = 0; ks < 2; ++ks)
        af[m][ks] = ldswz(Ab, wr * 128 + m * 16 + r16, ks * 32 + g * 8);
#pragma unroll
    for (int n = 0; n < 4; ++n)
#pragma unroll
      for (int ks = 0; ks < 2; ++ks)
        bfr[n][ks] = ldswz(Bb, wc * 64 + n * 16 + r16, ks * 32 + g * 8);

    // group 1: ks=0 (32 MFMA)
    __builtin_amdgcn_s_setprio(1);
#pragma unroll
    for (int m = 0; m < 8; ++m)
#pragma unroll
      for (int n = 0; n < 4; ++n)
        acc[m][n] = MFMA16(af[m][0], bfr[n][0], acc[m][n]);
    __builtin_amdgcn_s_setprio(0);

    // all our ds_reads complete -> barrier => whole block done reading buf[cur]
    asm volatile("s_waitcnt lgkmcnt(0)" ::: "memory");
    __builtin_amdgcn_s_barrier();
    __builtin_amdgcn_sched_barrier(0);

    if (t + 2 < ntk) stage(t + 2, cur);  // overwrite fully-read buffer (WAR-safe)
    __builtin_amdgcn_sched_barrier(0);

    // group 2: ks=1 (32 MFMA) — frags already in registers
    __builtin_amdgcn_s_setprio(1);
#pragma unroll
    for (int m = 0; m < 8; ++m)
#pragma unroll
      for (int n = 0; n < 4; ++n)
        acc[m][n] = MFMA16(af[m][1], bfr[n][1], acc[m][n]);
    __builtin_amdgcn_s_setprio(0);

    if (t + 1 < ntk) {  // boundary: tile t+1 resident; t+2's loads stay flying
      if (t + 2 < ntk) asm volatile("s_waitcnt vmcnt(8)" ::: "memory");
      else             asm volatile("s_waitcnt vmcnt(0)" ::: "memory");
      __builtin_amdgcn_s_barrier();
      __builtin_amdgcn_sched_barrier(0);
    }
    cur ^= 1;
  }

  // epilogue: per-frag C layout col = lane&15, row = (lane>>4)*4 + r
  if (EPI == 0) {
#pragma unroll
    for (int mt = 0; mt < 8; ++mt)
#pragma unroll
      for (int nt2 = 0; nt2 < 4; ++nt2)
#pragma unroll
        for (int r = 0; r < 4; ++r) {
          int m = m0 + wr * 128 + mt * 16 + g * 4 + r;
          int n = n0 + wc * 64 + nt2 * 16 + r16;
          Cf[(size_t)m * N + n] = acc[mt][nt2][r];
        }
  } else {
    const int which = (n0 + wc * 64) >> 10;  // wave-uniform (256|1024 aligned)
#pragma unroll
    for (int mt = 0; mt < 8; ++mt) {
      const int tb = m0 + wr * 128 + mt * 16 + g * 4;  // 4 consecutive m (=t)
      const int b = tb >> 11, t = tb & (ST - 1);
#pragma unroll
      for (int nt2 = 0; nt2 < 4; ++nt2) {
        int n = n0 + wc * 64 + nt2 * 16 + r16;
        int h = (n >> 6) & (SH - 1), d = n & (SD - 1);
        int bh = b * SH + h;
        if (which == 2) {  // VT[bh][d][t]: 4 consecutive t -> one 8B store
          ushortx4 o;
#pragma unroll
          for (int r = 0; r < 4; ++r) o[r] = f2bf(acc[mt][nt2][r]);
          *(ushortx4*)&VTo[((size_t)bh * SD + d) * ST + t] = o;
        } else if (which == 0) {
#pragma unroll
          for (int r = 0; r < 4; ++r)
            Qo[((size_t)bh * ST + t + r) * SD + d] = f2bf(acc[mt][nt2][r] * QSCALE);
        } else {
#pragma unroll
          for (int r = 0; r < 4; ++r)
            Ko[((size_t)bh * ST + t + r) * SD + d] = f2bf(acc[mt][nt2][r]);
        }
      }
    }
  }
}

// ---- NT GEMM small (R9-proven): 128x128, single-buffer, 256 thr ------------
// 2 blocks/CU, swizzled (0 conflicts). Used for GEMM2 (M=8192,N=1024,K=1024).
__global__ __launch_bounds__(256, 2) void gemm_sm(
    const unsigned short* __restrict__ A, const unsigned short* __restrict__ Bw,
    float* __restrict__ Cf, int M, int N, int K) {
  __shared__ unsigned short As[128 * 64];
  __shared__ unsigned short Bs[128 * 64];
  const int tid = threadIdx.x;
  const int lane = tid & 63;
  const int w = tid >> 6;
  const int wr = w >> 1, wc = w & 1;
  const int r16 = lane & 15, g = lane >> 4;

  const int nwg = gridDim.x * gridDim.y;
  const int lin = blockIdx.x + blockIdx.y * gridDim.x;
  const int wg = (lin & 7) * (nwg >> 3) + (lin >> 3);
  const int bx = wg % gridDim.x, by = wg / gridDim.x;
  const int m0 = by * 128, n0 = bx * 128;

  f32x4 acc[4][4] = {};

  for (int k0 = 0; k0 < K; k0 += 64) {
    __syncthreads();
#pragma unroll
    for (int it = 0; it < 4; ++it) {
      int c = it * 256 + tid;
      int row = c >> 3, j = c & 7;
      int src = ((j * 16) ^ ((row & 7) << 4)) >> 1;
      gll16(A + (size_t)(m0 + row) * K + k0 + src, As + c * 8);
    }
#pragma unroll
    for (int it = 0; it < 4; ++it) {
      int c = it * 256 + tid;
      int row = c >> 3, j = c & 7;
      int src = ((j * 16) ^ ((row & 7) << 4)) >> 1;
      gll16(Bw + (size_t)(n0 + row) * K + k0 + src, Bs + c * 8);
    }
    __syncthreads();
#pragma unroll
    for (int ks = 0; ks < 2; ++ks) {
      bf16x8 af[4], bfr[4];
#pragma unroll
      for (int mt = 0; mt < 4; ++mt)
        af[mt] = ldswz(As, wr * 64 + mt * 16 + r16, ks * 32 + g * 8);
#pragma unroll
      for (int nt2 = 0; nt2 < 4; ++nt2)
        bfr[nt2] = ldswz(Bs, wc * 64 + nt2 * 16 + r16, ks * 32 + g * 8);
#pragma unroll
      for (int mt = 0; mt < 4; ++mt)
#pragma unroll
        for (int nt2 = 0; nt2 < 4; ++nt2)
          acc[mt][nt2] = MFMA16(af[mt], bfr[nt2], acc[mt][nt2]);
    }
  }

#pragma unroll
  for (int mt = 0; mt < 4; ++mt)
#pragma unroll
    for (int nt2 = 0; nt2 < 4; ++nt2)
#pragma unroll
      for (int r = 0; r < 4; ++r) {
        int m = m0 + wr * 64 + mt * 16 + g * 4 + r;
        int n = n0 + wc * 64 + nt2 * 16 + r16;
        Cf[(size_t)m * N + n] = acc[mt][nt2][r];
      }
}

// ---- causal flash attention v8 (= R12 v6 body + balanced qt map) -----------
// QBLK=128 (4 waves x 32 q-cols), KVBLK=64, double-buffered K/V, XOR swizzle.
// 32x32x16 MFMA, swapped operands: S^T = mfma(K, Q). Softmax fully in-register;
// P redistributed to PV B-fragments via permlane32_swap (T12). exp2-domain,
// defer-max (T13). XCD-affinity: bh == xcd (mod 8) keeps each XCD's KV set in
// its 4 MB L2. NEW (R14): skewed qt map qt=(5*idx+4*(idx>>5))&15 -- any 4
// co-resident blocks' work-sums land in 22-38 tiles (ideal 30) under either
// contiguous or stride-32 CU fill; old map gave 0-60 (CU load imbalance,
// 32.5% avg occupancy).
// NOTE (R5/R13 post-mortems): NO seeded accumulator, NO extra acc state --
// both spill at the lb(256,4) 128-VGPR budget (R13: 405 MB scratch WRITE).
DEVI void stage_tile(const unsigned short* gbase, size_t rowstride,
                     unsigned short* lds, int tid) {
#pragma unroll
  for (int it = 0; it < 2; ++it) {
    int c = it * 256 + tid;
    int row = c >> 3, j = c & 7;
    int src = ((j * 16) ^ ((row & 7) << 4)) >> 1;  // shorts
    gll16(gbase + (size_t)row * rowstride + src, lds + c * 8);
  }
}

__global__ __launch_bounds__(256, 4) void attn_causal(
    const unsigned short* __restrict__ Q, const unsigned short* __restrict__ Kv,
    const unsigned short* __restrict__ VT, unsigned short* __restrict__ Y) {
  __shared__ unsigned short Ks[2][64 * 64];   // [t][d], swizzled
  __shared__ unsigned short Vs[2][64 * 64];   // [d][t], swizzled

  const int tid = threadIdx.x;
  const int lane = tid & 63;
  const int w = tid >> 6;
  const int l5 = lane & 31, h = lane >> 5;

  // XCD-affinity + balanced-load remap (see header comment)
  const int lin = blockIdx.x + blockIdx.y * gridDim.x;  // 0..1023
  const int xcd = lin & 7;
  const int idx = lin >> 3;                             // 0..127
  const int qt = (5 * idx + 4 * (idx >> 5)) & 15;
  const int bh = xcd + 8 * (idx >> 4);
  const size_t base = (size_t)bh * ST * SD;

  const int q_glob = qt * 128 + w * 32 + l5;   // this lane's q-row
  const int qwmin = qt * 128 + w * 32;         // wave q range [qwmin, qwmin+31]

  // Q B-fragments: col n = q = lane&31, k = h*8 + i, chained over kk (d-slices)
  bf16x8 qf[4];
#pragma unroll
  for (int kk = 0; kk < 4; ++kk)
    qf[kk] = ld8(Q + base + (size_t)q_glob * SD + kk * 16 + h * 8);

  float mrow = -__builtin_inff();
  float lrow = 0.f;
  f32x16 acc[2] = {};  // O^T: lane q=l5, d = dblk*32 + (reg&3) + 4h + 8*(reg>>2)

  const int nkv = 2 * qt + 2;
  stage_tile(Kv + base, SD, Ks[0], tid);
  stage_tile(VT + base, ST, Vs[0], tid);
  __syncthreads();

  for (int kvt = 0; kvt < nkv; ++kvt) {
    const int cur = kvt & 1;
    if (kvt + 1 < nkv) {  // prefetch next tile into other buffer
      stage_tile(Kv + base + (size_t)(kvt + 1) * 64 * SD, SD, Ks[cur ^ 1], tid);
      stage_tile(VT + base + (kvt + 1) * 64, ST, Vs[cur ^ 1], tid);
    }

    // tiles fully above this wave's q range contribute nothing
    const bool active = (kvt * 64) <= (qwmin + 31);
    if (active) {
      // S^T = K Q^T : two 32t x 32q blocks; lane owns q=l5, t-half per h
      f32x16 s0 = {}, s1 = {};
      __builtin_amdgcn_s_setprio(1);
#pragma unroll
      for (int kk = 0; kk < 4; ++kk) {
        bf16x8 k0 = ldswz(Ks[cur], l5, kk * 16 + h * 8);
        s0 = MFMA32(k0, qf[kk], s0);
      }
#pragma unroll
      for (int kk = 0; kk < 4; ++kk) {
        bf16x8 k1 = ldswz(Ks[cur], 32 + l5, kk * 16 + h * 8);
        s1 = MFMA32(k1, qf[kk], s1);
      }
      __builtin_amdgcn_s_setprio(0);

      if (kvt * 64 + 63 > qwmin) {  // diagonal overlap: causal mask
        const int t0 = kvt * 64 + 4 * h;
#pragma unroll
        for (int reg = 0; reg < 16; ++reg) {
          int t = t0 + (reg & 3) + 8 * (reg >> 2);
          if (t > q_glob) s0[reg] = -__builtin_inff();
          if (t + 32 > q_glob) s1[reg] = -__builtin_inff();
        }
      }

      // row max: elementwise + in-lane tree + one half-swap
      f32x16 mx;
#pragma unroll
      for (int i = 0; i < 16; ++i) mx[i] = fmaxf(s0[i], s1[i]);
#pragma unroll
      for (int i = 0; i < 8; ++i) mx[i] = fmaxf(mx[i], mx[i + 8]);
#pragma unroll
      for (int i = 0; i < 4; ++i) mx[i] = fmaxf(mx[i], mx[i + 4]);
      float bm = fmaxf(fmaxf(mx[0], mx[1]), fmaxf(mx[2], mx[3]));
      bm = swaphalf_max(bm);

      // defer-max: rescale only if running max grew by more than DMTHR
      if (__any(bm > mrow + DMTHR)) {
        float mn = fmaxf(mrow, bm);
        float corr = exp2f(mrow - mn);  // first tile: exp2(-inf)=0
        mrow = mn;
        lrow *= corr;
#pragma unroll
        for (int dblk = 0; dblk < 2; ++dblk)
#pragma unroll
          for (int i = 0; i < 16; ++i) acc[dblk][i] *= corr;
      }

      // P = exp2(S - m), in-lane sum + half-swap
#pragma unroll
      for (int i = 0; i < 16; ++i) {
        s0[i] = exp2f(s0[i] - mrow);
        s1[i] = exp2f(s1[i] - mrow);
      }
      f32x16 sm;
#pragma unroll
      for (int i = 0; i < 16; ++i) sm[i] = s0[i] + s1[i];
#pragma unroll
      for (int i = 0; i < 8; ++i) sm[i] += sm[i + 8];
#pragma unroll
      for (int i = 0; i < 4; ++i) sm[i] += sm[i + 4];
      float rs = (sm[0] + sm[1]) + (sm[2] + sm[3]);
      lrow += swaphalf_add(rs);

      // pack P -> bf16 PV B-fragments via permlane32_swap (no LDS roundtrip)
      bf16x8 pb[2][2];
      auto packblk = [&](const f32x16& S, bf16x8* out) {
        unsigned a = pkbf(S[0], S[1]), b2 = pkbf(S[2], S[3]);
        unsigned c = pkbf(S[4], S[5]), d2 = pkbf(S[6], S[7]);
        auto r0 = __builtin_amdgcn_permlane32_swap(a, c, false, false);
        auto r1 = __builtin_amdgcn_permlane32_swap(b2, d2, false, false);
        uint32x4v w0 = {(unsigned)r0[0], (unsigned)r1[0], (unsigned)r0[1], (unsigned)r1[1]};
        out[0] = __builtin_bit_cast(bf16x8, w0);
        unsigned e = pkbf(S[8], S[9]), f2 = pkbf(S[10], S[11]);
        unsigned g2 = pkbf(S[12], S[13]), h2 = pkbf(S[14], S[15]);
        auto r2 = __builtin_amdgcn_permlane32_swap(e, g2, false, false);
        auto r3 = __builtin_amdgcn_permlane32_swap(f2, h2, false, false);
        uint32x4v w1 = {(unsigned)r2[0], (unsigned)r3[0], (unsigned)r2[1], (unsigned)r3[1]};
        out[1] = __builtin_bit_cast(bf16x8, w1);
      };
      packblk(s0, pb[0]);
      packblk(s1, pb[1]);

      // O^T += V^T P^T : A = V^T (d rows), B = P^T (q cols)
      __builtin_amdgcn_s_setprio(1);
#pragma unroll
      for (int dblk = 0; dblk < 2; ++dblk)
#pragma unroll
        for (int tt = 0; tt < 2; ++tt)
#pragma unroll
          for (int sl = 0; sl < 2; ++sl) {
            bf16x8 va = ldswz(Vs[cur], dblk * 32 + l5, tt * 32 + sl * 16 + h * 8);
            acc[dblk] = MFMA32(va, pb[tt][sl], acc[dblk]);
          }
      __builtin_amdgcn_s_setprio(0);
    }

    __syncthreads();  // drains vmcnt (next tile staged) + guards buffer reuse
  }

  // epilogue: Y[B,T,E] bf16, e = head*64 + d; 4 consecutive d per reg-group
  const int b = bh >> 4, hd = bh & 15;
  const float inv = 1.f / lrow;
#pragma unroll
  for (int dblk = 0; dblk < 2; ++dblk)
#pragma unroll
    for (int rg = 0; rg < 4; ++rg) {
      bf16x4 o;
#pragma unroll
      for (int j = 0; j < 4; ++j) o[j] = (__bf16)(acc[dblk][rg * 4 + j] * inv);
      int d = dblk * 32 + rg * 8 + 4 * h;
      *(ushortx4*)&Y[((size_t)b * ST + q_glob) * SE + hd * SD + d] =
          __builtin_bit_cast(ushortx4, o);
    }
}

// ---- launch ----------------------------------------------------------------
extern "C" void kernel_launch(void* const* d_in, const int* in_sizes, int n_in,
                              void* d_out, int out_size, void* d_ws, size_t ws_size,
                              hipStream_t stream) {
  const float* x = (const float*)d_in[0];       // [4,2048,1024]
  const float* w_qkv = (const float*)d_in[1];   // [3072,1024]
  const float* w_out = (const float*)d_in[2];   // [1024,1024]
  float* out = (float*)d_out;                   // [4,2048,1024] f32

  const size_t NX = (size_t)SB * ST * SE;       // 8388608
  const size_t NQKV = (size_t)3 * SE * SE;      // 3145728
  const size_t NWO = (size_t)SE * SE;           // 1048576
  const size_t NHD = (size_t)SB * SH * ST * SD; // 8388608

  unsigned short* xb    = (unsigned short*)d_ws;        // 16MB, reused as Y later
  unsigned short* wqkvb = xb + NX;                      // 6MB
  unsigned short* woutb = wqkvb + NQKV;                 // 2MB
  unsigned short* q     = woutb + NWO;                  // 16MB
  unsigned short* k     = q + NHD;                      // 16MB
  unsigned short* vT    = k + NHD;                      // 16MB
  unsigned short* y     = xb;                           // alias (xb dead after GEMM1)

  const int ncvt = NXq4 + NQKVq4 + NWOq4;       // 3145728
  cvt_all<<<ncvt / 256, 256, 0, stream>>>(x, w_qkv, w_out, xb, wqkvb, woutb);

  // qkv = x @ w_qkv^T, scattered into Q/K/VT   (grid 12x32 = 384, %8==0)
  gemm_big<1><<<dim3(3 * SE / 256, SB * ST / 256), 512, 0, stream>>>(
      xb, wqkvb, nullptr, q, k, vT, SB * ST, 3 * SE, SE);

  attn_causal<<<dim3(ST / 128, SB * SH), 256, 0, stream>>>(q, k, vT, y);

  // out = y @ w_out^T (f32 out)   (R9-proven 128x128 kernel, 512 blocks)
  gemm_sm<<<dim3(SE / 128, SB * ST / 128), 256, 0, stream>>>(
      y, woutb, out, SB * ST, SE, SE);
}

// Round 15
// 181.626 us; speedup vs baseline: 1.6257x; 1.0260x over previous
//
#include <hip/hip_runtime.h>

// ---- types / helpers -------------------------------------------------------
typedef __bf16 bf16x8 __attribute__((ext_vector_type(8)));
typedef __bf16 bf16x4 __attribute__((ext_vector_type(4)));
typedef __bf16 bf16x2 __attribute__((ext_vector_type(2)));
typedef float f32x4 __attribute__((ext_vector_type(4)));
typedef float f32x16 __attribute__((ext_vector_type(16)));
typedef unsigned short ushortx8 __attribute__((ext_vector_type(8)));
typedef unsigned short ushortx4 __attribute__((ext_vector_type(4)));
typedef unsigned int uint32x4v __attribute__((ext_vector_type(4)));

#define DEVI static __device__ __forceinline__

DEVI unsigned short f2bf(float f) {  // round-to-nearest-even f32 -> bf16
  unsigned int u = __builtin_bit_cast(unsigned int, f);
  u += 0x7FFFu + ((u >> 16) & 1u);
  return (unsigned short)(u >> 16);
}

DEVI bf16x8 ld8(const unsigned short* p) {  // 16B vector load (global or LDS)
  return __builtin_bit_cast(bf16x8, *(const ushortx8*)p);
}

DEVI void gll16(const unsigned short* g, unsigned short* l) {  // global->LDS 16B DMA
  __builtin_amdgcn_global_load_lds((const __attribute__((address_space(1))) void*)g,
                                   (__attribute__((address_space(3))) void*)l, 16, 0, 0);
}

#define MFMA16(a, b, c) __builtin_amdgcn_mfma_f32_16x16x32_bf16(a, b, c, 0, 0, 0)
#define MFMA32(a, b, c) __builtin_amdgcn_mfma_f32_32x32x16_bf16(a, b, c, 0, 0, 0)

DEVI unsigned pkbf(float lo, float hi) {  // pack 2 f32 -> u32 of 2 bf16 (lo in low16)
  bf16x2 v;
  v[0] = (__bf16)lo;
  v[1] = (__bf16)hi;
  return __builtin_bit_cast(unsigned, v);
}

DEVI float swaphalf_max(float x) {  // max(own, other-32-lane-half) for all lanes
  unsigned xu = __builtin_bit_cast(unsigned, x);
  auto pr = __builtin_amdgcn_permlane32_swap(xu, xu, false, false);
  return fmaxf(__builtin_bit_cast(float, (unsigned)pr[0]),
               __builtin_bit_cast(float, (unsigned)pr[1]));
}

DEVI float swaphalf_add(float x) {
  unsigned xu = __builtin_bit_cast(unsigned, x);
  auto pr = __builtin_amdgcn_permlane32_swap(xu, xu, false, false);
  return __builtin_bit_cast(float, (unsigned)pr[0]) +
         __builtin_bit_cast(float, (unsigned)pr[1]);
}

// XOR-swizzled LDS read for 64-short (128 B) rows: byte ^= (row&7)<<4.
// Verified R7/R9: SQ_LDS_BANK_CONFLICT == 0 with the matching pre-swizzled src.
DEVI bf16x8 ldswz(const unsigned short* L, int row, int colsh) {
  return ld8(L + row * 64 + ((((colsh * 2) ^ ((row & 7) << 4))) >> 1));
}

// ---- problem constants -----------------------------------------------------
// B=4, T=2048, E=1024, H=16, D=64
#define SB 4
#define ST 2048
#define SE 1024
#define SH 16
#define SD 64
#define QSCALE 0.18033688011112042f  /* 0.125 * log2(e): Q pre-scale for exp2 softmax */
#define DMTHR 11.541560327111708f    /* defer-max threshold: 8 * log2(e) */

#define NXq4   2097152  /* (4*2048*1024)/4 */
#define NQKVq4  786432  /* (3*1024*1024)/4 */
#define NWOq4   262144  /* (1024*1024)/4 */

// ---- fused f32 -> bf16 convert (all three inputs, one launch) --------------
__global__ void cvt_all(const float* __restrict__ x, const float* __restrict__ wq,
                        const float* __restrict__ wo,
                        unsigned short* __restrict__ xb, unsigned short* __restrict__ wqb,
                        unsigned short* __restrict__ wob) {
  int i = blockIdx.x * blockDim.x + threadIdx.x;
  const float* src;
  unsigned short* dst;
  int j;
  if (i < NXq4) { src = x; dst = xb; j = i; }
  else if (i < NXq4 + NQKVq4) { src = wq; dst = wqb; j = i - NXq4; }
  else { src = wo; dst = wob; j = i - NXq4 - NQKVq4; }
  float4 v = ((const float4*)src)[j];
  ushortx4 o;
  o.x = f2bf(v.x); o.y = f2bf(v.y); o.z = f2bf(v.z); o.w = f2bf(v.w);
  ((ushortx4*)dst)[j] = o;
}

// ---- NT GEMM big: 256x256 tile, per-wave 128x64, counted-vmcnt dbuf --------
// R12-proven (~860 TF on GEMM1). Schedule (race-safe counted vmcnt, dbuf=2,
// depth-2 prefetch): read ALL 24 frags of tile t -> ks0 MFMAs -> lgkmcnt(0) +
// raw barrier (all waves done reading buf[cur]) -> stage tile t+2 INTO
// buf[cur] (WAR-safe) -> ks1 MFMAs -> vmcnt(8) [t+1 resident, t+2's 8 loads
// stay in flight -- never 0 mid-loop] -> barrier.
// 512 thr, 8 waves (2M x 4N), LDS 128 KB (1 block/CU), lb(512,2) => 256 VGPR.
// EPI==1: scatter qkv -> Q (xQSCALE), K, VT bf16 (VT packed 8B stores).
template<int EPI>
__global__ __launch_bounds__(512, 2) void gemm_big(
    const unsigned short* __restrict__ A, const unsigned short* __restrict__ Bw,
    float* __restrict__ Cf,
    unsigned short* __restrict__ Qo, unsigned short* __restrict__ Ko,
    unsigned short* __restrict__ VTo,
    int M, int N, int K) {
  __shared__ unsigned short As[2][256 * 64];  // 64 KB
  __shared__ unsigned short Bs[2][256 * 64];  // 64 KB
  const int tid = threadIdx.x;
  const int lane = tid & 63;
  const int w = tid >> 6;            // 0..7
  const int wr = w >> 2, wc = w & 3; // 2M x 4N
  const int r16 = lane & 15, g = lane >> 4;

  // XCD-aware remap: contiguous chunk per XCD (nwg=384, %8==0, bijective)
  const int nwg = gridDim.x * gridDim.y;
  const int lin = blockIdx.x + blockIdx.y * gridDim.x;
  const int wg = (lin & 7) * (nwg >> 3) + (lin >> 3);
  const int bx = wg % gridDim.x, by = wg / gridDim.x;
  const int m0 = by * 256, n0 = bx * 256;

  f32x4 acc[8][4] = {};

  // stage K-tile kt (256x64 A + 256x64 B), src pre-swizzled; 8 gll16/thread
  auto stage = [&](int kt, int buf) {
    const int k0 = kt << 6;
#pragma unroll
    for (int it = 0; it < 4; ++it) {
      int c = it * 512 + tid;          // 0..2047
      int row = c >> 3, j = c & 7;
      int src = ((j * 16) ^ ((row & 7) << 4)) >> 1;
      gll16(A + (size_t)(m0 + row) * K + k0 + src, As[buf] + c * 8);
    }
#pragma unroll
    for (int it = 0; it < 4; ++it) {
      int c = it * 512 + tid;
      int row = c >> 3, j = c & 7;
      int src = ((j * 16) ^ ((row & 7) << 4)) >> 1;
      gll16(Bw + (size_t)(n0 + row) * K + k0 + src, Bs[buf] + c * 8);
    }
  };

  const int ntk = K >> 6;  // 16
  stage(0, 0);
  stage(1, 1);
  asm volatile("s_waitcnt vmcnt(8)" ::: "memory");  // tile 0 resident
  __builtin_amdgcn_s_barrier();
  __builtin_amdgcn_sched_barrier(0);

  int cur = 0;
  for (int t = 0; t < ntk; ++t) {
    const unsigned short* Ab = As[cur];
    const unsigned short* Bb = Bs[cur];

    // read ALL fragments of this K-tile (24 x ds_read_b128)
    bf16x8 af[8][2], bfr[4][2];
#pragma unroll
    for (int m = 0; m < 8; ++m)
#pragma unroll
      for (int ks = 0; ks < 2; ++ks)
        af[m][ks] = ldswz(Ab, wr * 128 + m * 16 + r16, ks * 32 + g * 8);
#pragma unroll
    for (int n = 0; n < 4; ++n)
#pragma unroll
      for (int ks = 0; ks < 2; ++ks)
        bfr[n][ks] = ldswz(Bb, wc * 64 + n * 16 + r16, ks * 32 + g * 8);

    // group 1: ks=0 (32 MFMA)
    __builtin_amdgcn_s_setprio(1);
#pragma unroll
    for (int m = 0; m < 8; ++m)
#pragma unroll
      for (int n = 0; n < 4; ++n)
        acc[m][n] = MFMA16(af[m][0], bfr[n][0], acc[m][n]);
    __builtin_amdgcn_s_setprio(0);

    // all our ds_reads complete -> barrier => whole block done reading buf[cur]
    asm volatile("s_waitcnt lgkmcnt(0)" ::: "memory");
    __builtin_amdgcn_s_barrier();
    __builtin_amdgcn_sched_barrier(0);

    if (t + 2 < ntk) stage(t + 2, cur);  // overwrite fully-read buffer (WAR-safe)
    __builtin_amdgcn_sched_barrier(0);

    // group 2: ks=1 (32 MFMA) — frags already in registers
    __builtin_amdgcn_s_setprio(1);
#pragma unroll
    for (int m = 0; m < 8; ++m)
#pragma unroll
      for (int n = 0; n < 4; ++n)
        acc[m][n] = MFMA16(af[m][1], bfr[n][1], acc[m][n]);
    __builtin_amdgcn_s_setprio(0);

    if (t + 1 < ntk) {  // boundary: tile t+1 resident; t+2's loads stay flying
      if (t + 2 < ntk) asm volatile("s_waitcnt vmcnt(8)" ::: "memory");
      else             asm volatile("s_waitcnt vmcnt(0)" ::: "memory");
      __builtin_amdgcn_s_barrier();
      __builtin_amdgcn_sched_barrier(0);
    }
    cur ^= 1;
  }

  // epilogue: per-frag C layout col = lane&15, row = (lane>>4)*4 + r
  if (EPI == 0) {
#pragma unroll
    for (int mt = 0; mt < 8; ++mt)
#pragma unroll
      for (int nt2 = 0; nt2 < 4; ++nt2)
#pragma unroll
        for (int r = 0; r < 4; ++r) {
          int m = m0 + wr * 128 + mt * 16 + g * 4 + r;
          int n = n0 + wc * 64 + nt2 * 16 + r16;
          Cf[(size_t)m * N + n] = acc[mt][nt2][r];
        }
  } else {
    const int which = (n0 + wc * 64) >> 10;  // wave-uniform (256|1024 aligned)
#pragma unroll
    for (int mt = 0; mt < 8; ++mt) {
      const int tb = m0 + wr * 128 + mt * 16 + g * 4;  // 4 consecutive m (=t)
      const int b = tb >> 11, t = tb & (ST - 1);
#pragma unroll
      for (int nt2 = 0; nt2 < 4; ++nt2) {
        int n = n0 + wc * 64 + nt2 * 16 + r16;
        int h = (n >> 6) & (SH - 1), d = n & (SD - 1);
        int bh = b * SH + h;
        if (which == 2) {  // VT[bh][d][t]: 4 consecutive t -> one 8B store
          ushortx4 o;
#pragma unroll
          for (int r = 0; r < 4; ++r) o[r] = f2bf(acc[mt][nt2][r]);
          *(ushortx4*)&VTo[((size_t)bh * SD + d) * ST + t] = o;
        } else if (which == 0) {
#pragma unroll
          for (int r = 0; r < 4; ++r)
            Qo[((size_t)bh * ST + t + r) * SD + d] = f2bf(acc[mt][nt2][r] * QSCALE);
        } else {
#pragma unroll
          for (int r = 0; r < 4; ++r)
            Ko[((size_t)bh * ST + t + r) * SD + d] = f2bf(acc[mt][nt2][r]);
        }
      }
    }
  }
}

// ---- NT GEMM small (R9-proven): 128x128, single-buffer, 256 thr ------------
// 2 blocks/CU, swizzled (0 conflicts). Used for GEMM2 (M=8192,N=1024,K=1024).
__global__ __launch_bounds__(256, 2) void gemm_sm(
    const unsigned short* __restrict__ A, const unsigned short* __restrict__ Bw,
    float* __restrict__ Cf, int M, int N, int K) {
  __shared__ unsigned short As[128 * 64];
  __shared__ unsigned short Bs[128 * 64];
  const int tid = threadIdx.x;
  const int lane = tid & 63;
  const int w = tid >> 6;
  const int wr = w >> 1, wc = w & 1;
  const int r16 = lane & 15, g = lane >> 4;

  const int nwg = gridDim.x * gridDim.y;
  const int lin = blockIdx.x + blockIdx.y * gridDim.x;
  const int wg = (lin & 7) * (nwg >> 3) + (lin >> 3);
  const int bx = wg % gridDim.x, by = wg / gridDim.x;
  const int m0 = by * 128, n0 = bx * 128;

  f32x4 acc[4][4] = {};

  for (int k0 = 0; k0 < K; k0 += 64) {
    __syncthreads();
#pragma unroll
    for (int it = 0; it < 4; ++it) {
      int c = it * 256 + tid;
      int row = c >> 3, j = c & 7;
      int src = ((j * 16) ^ ((row & 7) << 4)) >> 1;
      gll16(A + (size_t)(m0 + row) * K + k0 + src, As + c * 8);
    }
#pragma unroll
    for (int it = 0; it < 4; ++it) {
      int c = it * 256 + tid;
      int row = c >> 3, j = c & 7;
      int src = ((j * 16) ^ ((row & 7) << 4)) >> 1;
      gll16(Bw + (size_t)(n0 + row) * K + k0 + src, Bs + c * 8);
    }
    __syncthreads();
#pragma unroll
    for (int ks = 0; ks < 2; ++ks) {
      bf16x8 af[4], bfr[4];
#pragma unroll
      for (int mt = 0; mt < 4; ++mt)
        af[mt] = ldswz(As, wr * 64 + mt * 16 + r16, ks * 32 + g * 8);
#pragma unroll
      for (int nt2 = 0; nt2 < 4; ++nt2)
        bfr[nt2] = ldswz(Bs, wc * 64 + nt2 * 16 + r16, ks * 32 + g * 8);
#pragma unroll
      for (int mt = 0; mt < 4; ++mt)
#pragma unroll
        for (int nt2 = 0; nt2 < 4; ++nt2)
          acc[mt][nt2] = MFMA16(af[mt], bfr[nt2], acc[mt][nt2]);
    }
  }

#pragma unroll
  for (int mt = 0; mt < 4; ++mt)
#pragma unroll
    for (int nt2 = 0; nt2 < 4; ++nt2)
#pragma unroll
      for (int r = 0; r < 4; ++r) {
        int m = m0 + wr * 64 + mt * 16 + g * 4 + r;
        int n = n0 + wc * 64 + nt2 * 16 + r16;
        Cf[(size_t)m * N + n] = acc[mt][nt2][r];
      }
}

// ---- causal flash attention v9 (= R12 v6 body, QBLK=256 / 8 waves) ---------
// QBLK=256 (8 waves x 32 q-cols), KVBLK=64, double-buffered K/V, XOR swizzle.
// 32x32x16 MFMA, swapped operands: S^T = mfma(K, Q). Softmax fully in-register;
// P redistributed to PV B-fragments via permlane32_swap (T12). exp2-domain,
// defer-max (T13). XCD-affinity (R12-proven map shape): bh == xcd (mod 8), J
// (q-supertile) descending -> heavy blocks first. QBLK 128->256 halves total
// KV staging work per head (sum 272 -> 144 tiles): each staged tile feeds 8
// waves instead of 4. Occupancy: 512 blocks, 2/CU, 16 waves/CU (unchanged).
// NOTE (R5/R13 post-mortems): NO seeded accumulator, NO extra acc state --
// both spill (R13: 405 MB scratch WRITE). R14: no scheduler-guess remaps.
DEVI void stage_tile(const unsigned short* gbase, size_t rowstride,
                     unsigned short* lds, int tid) {
  // one 64x64 bf16 tile = 8 KB = 512 threads x 16 B, single round
  int row = tid >> 3, j = tid & 7;
  int src = ((j * 16) ^ ((row & 7) << 4)) >> 1;  // shorts (pre-swizzled)
  gll16(gbase + (size_t)row * rowstride + src, lds + tid * 8);
}

__global__ __launch_bounds__(512, 4) void attn_causal(
    const unsigned short* __restrict__ Q, const unsigned short* __restrict__ Kv,
    const unsigned short* __restrict__ VT, unsigned short* __restrict__ Y) {
  __shared__ unsigned short Ks[2][64 * 64];   // [t][d], swizzled
  __shared__ unsigned short Vs[2][64 * 64];   // [d][t], swizzled

  const int tid = threadIdx.x;
  const int lane = tid & 63;
  const int w = tid >> 6;                     // 0..7
  const int l5 = lane & 31, h = lane >> 5;

  // XCD-affinity remap (R12 shape): xcd = lin&7 handles heads {xcd, xcd+8,..};
  // J descending -> all 64 heads' heaviest blocks dispatch first.
  const int lin = blockIdx.x + blockIdx.y * gridDim.x;  // 0..511
  const int xcd = lin & 7;
  const int idx = lin >> 3;                 // 0..63
  const int J = (ST / 256 - 1) - (idx >> 3);  // q supertile, 7..0
  const int bh = xcd + 8 * (idx & 7);
  const size_t base = (size_t)bh * ST * SD;

  const int q_glob = J * 256 + w * 32 + l5;   // this lane's q-row
  const int qwmin = J * 256 + w * 32;         // wave q range [qwmin, qwmin+31]

  // Q B-fragments: col n = q = lane&31, k = h*8 + i, chained over kk (d-slices)
  bf16x8 qf[4];
#pragma unroll
  for (int kk = 0; kk < 4; ++kk)
    qf[kk] = ld8(Q + base + (size_t)q_glob * SD + kk * 16 + h * 8);

  float mrow = -__builtin_inff();
  float lrow = 0.f;
  f32x16 acc[2] = {};  // O^T: lane q=l5, d = dblk*32 + (reg&3) + 4h + 8*(reg>>2)

  const int nkv = 4 * J + 4;
  stage_tile(Kv + base, SD, Ks[0], tid);
  stage_tile(VT + base, ST, Vs[0], tid);
  __syncthreads();

  for (int kvt = 0; kvt < nkv; ++kvt) {
    const int cur = kvt & 1;
    if (kvt + 1 < nkv) {  // prefetch next tile into other buffer
      stage_tile(Kv + base + (size_t)(kvt + 1) * 64 * SD, SD, Ks[cur ^ 1], tid);
      stage_tile(VT + base + (kvt + 1) * 64, ST, Vs[cur ^ 1], tid);
    }

    // tiles fully above this wave's q range contribute nothing
    const bool active = (kvt * 64) <= (qwmin + 31);
    if (active) {
      // S^T = K Q^T : two 32t x 32q blocks; lane owns q=l5, t-half per h
      f32x16 s0 = {}, s1 = {};
      __builtin_amdgcn_s_setprio(1);
#pragma unroll
      for (int kk = 0; kk < 4; ++kk) {
        bf16x8 k0 = ldswz(Ks[cur], l5, kk * 16 + h * 8);
        s0 = MFMA32(k0, qf[kk], s0);
      }
#pragma unroll
      for (int kk = 0; kk < 4; ++kk) {
        bf16x8 k1 = ldswz(Ks[cur], 32 + l5, kk * 16 + h * 8);
        s1 = MFMA32(k1, qf[kk], s1);
      }
      __builtin_amdgcn_s_setprio(0);

      if (kvt * 64 + 63 > qwmin) {  // diagonal overlap: causal mask
        const int t0 = kvt * 64 + 4 * h;
#pragma unroll
        for (int reg = 0; reg < 16; ++reg) {
          int t = t0 + (reg & 3) + 8 * (reg >> 2);
          if (t > q_glob) s0[reg] = -__builtin_inff();
          if (t + 32 > q_glob) s1[reg] = -__builtin_inff();
        }
      }

      // row max: elementwise + in-lane tree + one half-swap
      f32x16 mx;
#pragma unroll
      for (int i = 0; i < 16; ++i) mx[i] = fmaxf(s0[i], s1[i]);
#pragma unroll
      for (int i = 0; i < 8; ++i) mx[i] = fmaxf(mx[i], mx[i + 8]);
#pragma unroll
      for (int i = 0; i < 4; ++i) mx[i] = fmaxf(mx[i], mx[i + 4]);
      float bm = fmaxf(fmaxf(mx[0], mx[1]), fmaxf(mx[2], mx[3]));
      bm = swaphalf_max(bm);

      // defer-max: rescale only if running max grew by more than DMTHR
      if (__any(bm > mrow + DMTHR)) {
        float mn = fmaxf(mrow, bm);
        float corr = exp2f(mrow - mn);  // first tile: exp2(-inf)=0
        mrow = mn;
        lrow *= corr;
#pragma unroll
        for (int dblk = 0; dblk < 2; ++dblk)
#pragma unroll
          for (int i = 0; i < 16; ++i) acc[dblk][i] *= corr;
      }

      // P = exp2(S - m), in-lane sum + half-swap
#pragma unroll
      for (int i = 0; i < 16; ++i) {
        s0[i] = exp2f(s0[i] - mrow);
        s1[i] = exp2f(s1[i] - mrow);
      }
      f32x16 sm;
#pragma unroll
      for (int i = 0; i < 16; ++i) sm[i] = s0[i] + s1[i];
#pragma unroll
      for (int i = 0; i < 8; ++i) sm[i] += sm[i + 8];
#pragma unroll
      for (int i = 0; i < 4; ++i) sm[i] += sm[i + 4];
      float rs = (sm[0] + sm[1]) + (sm[2] + sm[3]);
      lrow += swaphalf_add(rs);

      // pack P -> bf16 PV B-fragments via permlane32_swap (no LDS roundtrip)
      bf16x8 pb[2][2];
      auto packblk = [&](const f32x16& S, bf16x8* out) {
        unsigned a = pkbf(S[0], S[1]), b2 = pkbf(S[2], S[3]);
        unsigned c = pkbf(S[4], S[5]), d2 = pkbf(S[6], S[7]);
        auto r0 = __builtin_amdgcn_permlane32_swap(a, c, false, false);
        auto r1 = __builtin_amdgcn_permlane32_swap(b2, d2, false, false);
        uint32x4v w0 = {(unsigned)r0[0], (unsigned)r1[0], (unsigned)r0[1], (unsigned)r1[1]};
        out[0] = __builtin_bit_cast(bf16x8, w0);
        unsigned e = pkbf(S[8], S[9]), f2 = pkbf(S[10], S[11]);
        unsigned g2 = pkbf(S[12], S[13]), h2 = pkbf(S[14], S[15]);
        auto r2 = __builtin_amdgcn_permlane32_swap(e, g2, false, false);
        auto r3 = __builtin_amdgcn_permlane32_swap(f2, h2, false, false);
        uint32x4v w1 = {(unsigned)r2[0], (unsigned)r3[0], (unsigned)r2[1], (unsigned)r3[1]};
        out[1] = __builtin_bit_cast(bf16x8, w1);
      };
      packblk(s0, pb[0]);
      packblk(s1, pb[1]);

      // O^T += V^T P^T : A = V^T (d rows), B = P^T (q cols)
      __builtin_amdgcn_s_setprio(1);
#pragma unroll
      for (int dblk = 0; dblk < 2; ++dblk)
#pragma unroll
        for (int tt = 0; tt < 2; ++tt)
#pragma unroll
          for (int sl = 0; sl < 2; ++sl) {
            bf16x8 va = ldswz(Vs[cur], dblk * 32 + l5, tt * 32 + sl * 16 + h * 8);
            acc[dblk] = MFMA32(va, pb[tt][sl], acc[dblk]);
          }
      __builtin_amdgcn_s_setprio(0);
    }

    __syncthreads();  // drains vmcnt (next tile staged) + guards buffer reuse
  }

  // epilogue: Y[B,T,E] bf16, e = head*64 + d; 4 consecutive d per reg-group
  const int b = bh >> 4, hd = bh & 15;
  const float inv = 1.f / lrow;
#pragma unroll
  for (int dblk = 0; dblk < 2; ++dblk)
#pragma unroll
    for (int rg = 0; rg < 4; ++rg) {
      bf16x4 o;
#pragma unroll
      for (int j = 0; j < 4; ++j) o[j] = (__bf16)(acc[dblk][rg * 4 + j] * inv);
      int d = dblk * 32 + rg * 8 + 4 * h;
      *(ushortx4*)&Y[((size_t)b * ST + q_glob) * SE + hd * SD + d] =
          __builtin_bit_cast(ushortx4, o);
    }
}

// ---- launch ----------------------------------------------------------------
extern "C" void kernel_launch(void* const* d_in, const int* in_sizes, int n_in,
                              void* d_out, int out_size, void* d_ws, size_t ws_size,
                              hipStream_t stream) {
  const float* x = (const float*)d_in[0];       // [4,2048,1024]
  const float* w_qkv = (const float*)d_in[1];   // [3072,1024]
  const float* w_out = (const float*)d_in[2];   // [1024,1024]
  float* out = (float*)d_out;                   // [4,2048,1024] f32

  const size_t NX = (size_t)SB * ST * SE;       // 8388608
  const size_t NQKV = (size_t)3 * SE * SE;      // 3145728
  const size_t NWO = (size_t)SE * SE;           // 1048576
  const size_t NHD = (size_t)SB * SH * ST * SD; // 8388608

  unsigned short* xb    = (unsigned short*)d_ws;        // 16MB, reused as Y later
  unsigned short* wqkvb = xb + NX;                      // 6MB
  unsigned short* woutb = wqkvb + NQKV;                 // 2MB
  unsigned short* q     = woutb + NWO;                  // 16MB
  unsigned short* k     = q + NHD;                      // 16MB
  unsigned short* vT    = k + NHD;                      // 16MB
  unsigned short* y     = xb;                           // alias (xb dead after GEMM1)

  const int ncvt = NXq4 + NQKVq4 + NWOq4;       // 3145728
  cvt_all<<<ncvt / 256, 256, 0, stream>>>(x, w_qkv, w_out, xb, wqkvb, woutb);

  // qkv = x @ w_qkv^T, scattered into Q/K/VT   (grid 12x32 = 384, %8==0)
  gemm_big<1><<<dim3(3 * SE / 256, SB * ST / 256), 512, 0, stream>>>(
      xb, wqkvb, nullptr, q, k, vT, SB * ST, 3 * SE, SE);

  // attention: QBLK=256, grid 2x... (ST/256=8, 64 heads) = 512 blocks
  attn_causal<<<dim3(ST / 256, SB * SH), 512, 0, stream>>>(q, k, vT, y);

  // out = y @ w_out^T (f32 out)   (R9-proven 128x128 kernel, 512 blocks)
  gemm_sm<<<dim3(SE / 128, SB * ST / 128), 256, 0, stream>>>(
      y, woutb, out, SB * ST, SE, SE);
}

// Round 16
// 174.898 us; speedup vs baseline: 1.6883x; 1.0385x over previous
//
#include <hip/hip_runtime.h>

// ---- types / helpers -------------------------------------------------------
typedef __bf16 bf16x8 __attribute__((ext_vector_type(8)));
typedef __bf16 bf16x4 __attribute__((ext_vector_type(4)));
typedef __bf16 bf16x2 __attribute__((ext_vector_type(2)));
typedef float f32x4 __attribute__((ext_vector_type(4)));
typedef float f32x16 __attribute__((ext_vector_type(16)));
typedef unsigned short ushortx8 __attribute__((ext_vector_type(8)));
typedef unsigned short ushortx4 __attribute__((ext_vector_type(4)));
typedef unsigned int uint32x4v __attribute__((ext_vector_type(4)));

#define DEVI static __device__ __forceinline__

DEVI unsigned short f2bf(float f) {  // round-to-nearest-even f32 -> bf16
  unsigned int u = __builtin_bit_cast(unsigned int, f);
  u += 0x7FFFu + ((u >> 16) & 1u);
  return (unsigned short)(u >> 16);
}

DEVI bf16x8 ld8(const unsigned short* p) {  // 16B vector load (global or LDS)
  return __builtin_bit_cast(bf16x8, *(const ushortx8*)p);
}

DEVI void gll16(const unsigned short* g, unsigned short* l) {  // global->LDS 16B DMA
  __builtin_amdgcn_global_load_lds((const __attribute__((address_space(1))) void*)g,
                                   (__attribute__((address_space(3))) void*)l, 16, 0, 0);
}

#define MFMA16(a, b, c) __builtin_amdgcn_mfma_f32_16x16x32_bf16(a, b, c, 0, 0, 0)
#define MFMA32(a, b, c) __builtin_amdgcn_mfma_f32_32x32x16_bf16(a, b, c, 0, 0, 0)

DEVI unsigned pkbf(float lo, float hi) {  // pack 2 f32 -> u32 of 2 bf16 (lo in low16)
  bf16x2 v;
  v[0] = (__bf16)lo;
  v[1] = (__bf16)hi;
  return __builtin_bit_cast(unsigned, v);
}

DEVI float swaphalf_max(float x) {  // max(own, other-32-lane-half) for all lanes
  unsigned xu = __builtin_bit_cast(unsigned, x);
  auto pr = __builtin_amdgcn_permlane32_swap(xu, xu, false, false);
  return fmaxf(__builtin_bit_cast(float, (unsigned)pr[0]),
               __builtin_bit_cast(float, (unsigned)pr[1]));
}

DEVI float swaphalf_add(float x) {
  unsigned xu = __builtin_bit_cast(unsigned, x);
  auto pr = __builtin_amdgcn_permlane32_swap(xu, xu, false, false);
  return __builtin_bit_cast(float, (unsigned)pr[0]) +
         __builtin_bit_cast(float, (unsigned)pr[1]);
}

// XOR-swizzled LDS read for 64-short (128 B) rows: byte ^= (row&7)<<4.
// Verified R7/R9: SQ_LDS_BANK_CONFLICT == 0 with the matching pre-swizzled src.
DEVI bf16x8 ldswz(const unsigned short* L, int row, int colsh) {
  return ld8(L + row * 64 + ((((colsh * 2) ^ ((row & 7) << 4))) >> 1));
}

// ---- problem constants -----------------------------------------------------
// B=4, T=2048, E=1024, H=16, D=64
#define SB 4
#define ST 2048
#define SE 1024
#define SH 16
#define SD 64
#define QSCALE 0.18033688011112042f  /* 0.125 * log2(e): Q pre-scale for exp2 softmax */
#define DMTHR 11.541560327111708f    /* defer-max threshold: 8 * log2(e) */

#define NXq4   2097152  /* (4*2048*1024)/4 */
#define NQKVq4  786432  /* (3*1024*1024)/4 */
#define NWOq4   262144  /* (1024*1024)/4 */

// ---- fused f32 -> bf16 convert (all three inputs, one launch) --------------
__global__ void cvt_all(const float* __restrict__ x, const float* __restrict__ wq,
                        const float* __restrict__ wo,
                        unsigned short* __restrict__ xb, unsigned short* __restrict__ wqb,
                        unsigned short* __restrict__ wob) {
  int i = blockIdx.x * blockDim.x + threadIdx.x;
  const float* src;
  unsigned short* dst;
  int j;
  if (i < NXq4) { src = x; dst = xb; j = i; }
  else if (i < NXq4 + NQKVq4) { src = wq; dst = wqb; j = i - NXq4; }
  else { src = wo; dst = wob; j = i - NXq4 - NQKVq4; }
  float4 v = ((const float4*)src)[j];
  ushortx4 o;
  o.x = f2bf(v.x); o.y = f2bf(v.y); o.z = f2bf(v.z); o.w = f2bf(v.w);
  ((ushortx4*)dst)[j] = o;
}

// ---- NT GEMM big: 256x256 tile, per-wave 128x64, counted-vmcnt dbuf --------
// R12-proven (~860 TF on GEMM1). Schedule (race-safe counted vmcnt, dbuf=2,
// depth-2 prefetch): read ALL 24 frags of tile t -> ks0 MFMAs -> lgkmcnt(0) +
// raw barrier (all waves done reading buf[cur]) -> stage tile t+2 INTO
// buf[cur] (WAR-safe) -> ks1 MFMAs -> vmcnt(8) [t+1 resident, t+2's 8 loads
// stay in flight -- never 0 mid-loop] -> barrier.
// 512 thr, 8 waves (2M x 4N), LDS 128 KB (1 block/CU), lb(512,2) => 256 VGPR.
// EPI==1: scatter qkv -> Q (xQSCALE), K, VT bf16 (VT packed 8B stores).
template<int EPI>
__global__ __launch_bounds__(512, 2) void gemm_big(
    const unsigned short* __restrict__ A, const unsigned short* __restrict__ Bw,
    float* __restrict__ Cf,
    unsigned short* __restrict__ Qo, unsigned short* __restrict__ Ko,
    unsigned short* __restrict__ VTo,
    int M, int N, int K) {
  __shared__ unsigned short As[2][256 * 64];  // 64 KB
  __shared__ unsigned short Bs[2][256 * 64];  // 64 KB
  const int tid = threadIdx.x;
  const int lane = tid & 63;
  const int w = tid >> 6;            // 0..7
  const int wr = w >> 2, wc = w & 3; // 2M x 4N
  const int r16 = lane & 15, g = lane >> 4;

  // XCD-aware remap: contiguous chunk per XCD (nwg=384, %8==0, bijective)
  const int nwg = gridDim.x * gridDim.y;
  const int lin = blockIdx.x + blockIdx.y * gridDim.x;
  const int wg = (lin & 7) * (nwg >> 3) + (lin >> 3);
  const int bx = wg % gridDim.x, by = wg / gridDim.x;
  const int m0 = by * 256, n0 = bx * 256;

  f32x4 acc[8][4] = {};

  // stage K-tile kt (256x64 A + 256x64 B), src pre-swizzled; 8 gll16/thread
  auto stage = [&](int kt, int buf) {
    const int k0 = kt << 6;
#pragma unroll
    for (int it = 0; it < 4; ++it) {
      int c = it * 512 + tid;          // 0..2047
      int row = c >> 3, j = c & 7;
      int src = ((j * 16) ^ ((row & 7) << 4)) >> 1;
      gll16(A + (size_t)(m0 + row) * K + k0 + src, As[buf] + c * 8);
    }
#pragma unroll
    for (int it = 0; it < 4; ++it) {
      int c = it * 512 + tid;
      int row = c >> 3, j = c & 7;
      int src = ((j * 16) ^ ((row & 7) << 4)) >> 1;
      gll16(Bw + (size_t)(n0 + row) * K + k0 + src, Bs[buf] + c * 8);
    }
  };

  const int ntk = K >> 6;  // 16
  stage(0, 0);
  stage(1, 1);
  asm volatile("s_waitcnt vmcnt(8)" ::: "memory");  // tile 0 resident
  __builtin_amdgcn_s_barrier();
  __builtin_amdgcn_sched_barrier(0);

  int cur = 0;
  for (int t = 0; t < ntk; ++t) {
    const unsigned short* Ab = As[cur];
    const unsigned short* Bb = Bs[cur];

    // read ALL fragments of this K-tile (24 x ds_read_b128)
    bf16x8 af[8][2], bfr[4][2];
#pragma unroll
    for (int m = 0; m < 8; ++m)
#pragma unroll
      for (int ks = 0; ks < 2; ++ks)
        af[m][ks] = ldswz(Ab, wr * 128 + m * 16 + r16, ks * 32 + g * 8);
#pragma unroll
    for (int n = 0; n < 4; ++n)
#pragma unroll
      for (int ks = 0; ks < 2; ++ks)
        bfr[n][ks] = ldswz(Bb, wc * 64 + n * 16 + r16, ks * 32 + g * 8);

    // group 1: ks=0 (32 MFMA)
    __builtin_amdgcn_s_setprio(1);
#pragma unroll
    for (int m = 0; m < 8; ++m)
#pragma unroll
      for (int n = 0; n < 4; ++n)
        acc[m][n] = MFMA16(af[m][0], bfr[n][0], acc[m][n]);
    __builtin_amdgcn_s_setprio(0);

    // all our ds_reads complete -> barrier => whole block done reading buf[cur]
    asm volatile("s_waitcnt lgkmcnt(0)" ::: "memory");
    __builtin_amdgcn_s_barrier();
    __builtin_amdgcn_sched_barrier(0);

    if (t + 2 < ntk) stage(t + 2, cur);  // overwrite fully-read buffer (WAR-safe)
    __builtin_amdgcn_sched_barrier(0);

    // group 2: ks=1 (32 MFMA) — frags already in registers
    __builtin_amdgcn_s_setprio(1);
#pragma unroll
    for (int m = 0; m < 8; ++m)
#pragma unroll
      for (int n = 0; n < 4; ++n)
        acc[m][n] = MFMA16(af[m][1], bfr[n][1], acc[m][n]);
    __builtin_amdgcn_s_setprio(0);

    if (t + 1 < ntk) {  // boundary: tile t+1 resident; t+2's loads stay flying
      if (t + 2 < ntk) asm volatile("s_waitcnt vmcnt(8)" ::: "memory");
      else             asm volatile("s_waitcnt vmcnt(0)" ::: "memory");
      __builtin_amdgcn_s_barrier();
      __builtin_amdgcn_sched_barrier(0);
    }
    cur ^= 1;
  }

  // epilogue: per-frag C layout col = lane&15, row = (lane>>4)*4 + r
  if (EPI == 0) {
#pragma unroll
    for (int mt = 0; mt < 8; ++mt)
#pragma unroll
      for (int nt2 = 0; nt2 < 4; ++nt2)
#pragma unroll
        for (int r = 0; r < 4; ++r) {
          int m = m0 + wr * 128 + mt * 16 + g * 4 + r;
          int n = n0 + wc * 64 + nt2 * 16 + r16;
          Cf[(size_t)m * N + n] = acc[mt][nt2][r];
        }
  } else {
    const int which = (n0 + wc * 64) >> 10;  // wave-uniform (256|1024 aligned)
#pragma unroll
    for (int mt = 0; mt < 8; ++mt) {
      const int tb = m0 + wr * 128 + mt * 16 + g * 4;  // 4 consecutive m (=t)
      const int b = tb >> 11, t = tb & (ST - 1);
#pragma unroll
      for (int nt2 = 0; nt2 < 4; ++nt2) {
        int n = n0 + wc * 64 + nt2 * 16 + r16;
        int h = (n >> 6) & (SH - 1), d = n & (SD - 1);
        int bh = b * SH + h;
        if (which == 2) {  // VT[bh][d][t]: 4 consecutive t -> one 8B store
          ushortx4 o;
#pragma unroll
          for (int r = 0; r < 4; ++r) o[r] = f2bf(acc[mt][nt2][r]);
          *(ushortx4*)&VTo[((size_t)bh * SD + d) * ST + t] = o;
        } else if (which == 0) {
#pragma unroll
          for (int r = 0; r < 4; ++r)
            Qo[((size_t)bh * ST + t + r) * SD + d] = f2bf(acc[mt][nt2][r] * QSCALE);
        } else {
#pragma unroll
          for (int r = 0; r < 4; ++r)
            Ko[((size_t)bh * ST + t + r) * SD + d] = f2bf(acc[mt][nt2][r]);
        }
      }
    }
  }
}

// ---- NT GEMM small (R9-proven): 128x128, single-buffer, 256 thr ------------
// 2 blocks/CU, swizzled (0 conflicts). Used for GEMM2 (M=8192,N=1024,K=1024).
__global__ __launch_bounds__(256, 2) void gemm_sm(
    const unsigned short* __restrict__ A, const unsigned short* __restrict__ Bw,
    float* __restrict__ Cf, int M, int N, int K) {
  __shared__ unsigned short As[128 * 64];
  __shared__ unsigned short Bs[128 * 64];
  const int tid = threadIdx.x;
  const int lane = tid & 63;
  const int w = tid >> 6;
  const int wr = w >> 1, wc = w & 1;
  const int r16 = lane & 15, g = lane >> 4;

  const int nwg = gridDim.x * gridDim.y;
  const int lin = blockIdx.x + blockIdx.y * gridDim.x;
  const int wg = (lin & 7) * (nwg >> 3) + (lin >> 3);
  const int bx = wg % gridDim.x, by = wg / gridDim.x;
  const int m0 = by * 128, n0 = bx * 128;

  f32x4 acc[4][4] = {};

  for (int k0 = 0; k0 < K; k0 += 64) {
    __syncthreads();
#pragma unroll
    for (int it = 0; it < 4; ++it) {
      int c = it * 256 + tid;
      int row = c >> 3, j = c & 7;
      int src = ((j * 16) ^ ((row & 7) << 4)) >> 1;
      gll16(A + (size_t)(m0 + row) * K + k0 + src, As + c * 8);
    }
#pragma unroll
    for (int it = 0; it < 4; ++it) {
      int c = it * 256 + tid;
      int row = c >> 3, j = c & 7;
      int src = ((j * 16) ^ ((row & 7) << 4)) >> 1;
      gll16(Bw + (size_t)(n0 + row) * K + k0 + src, Bs + c * 8);
    }
    __syncthreads();
#pragma unroll
    for (int ks = 0; ks < 2; ++ks) {
      bf16x8 af[4], bfr[4];
#pragma unroll
      for (int mt = 0; mt < 4; ++mt)
        af[mt] = ldswz(As, wr * 64 + mt * 16 + r16, ks * 32 + g * 8);
#pragma unroll
      for (int nt2 = 0; nt2 < 4; ++nt2)
        bfr[nt2] = ldswz(Bs, wc * 64 + nt2 * 16 + r16, ks * 32 + g * 8);
#pragma unroll
      for (int mt = 0; mt < 4; ++mt)
#pragma unroll
        for (int nt2 = 0; nt2 < 4; ++nt2)
          acc[mt][nt2] = MFMA16(af[mt], bfr[nt2], acc[mt][nt2]);
    }
  }

#pragma unroll
  for (int mt = 0; mt < 4; ++mt)
#pragma unroll
    for (int nt2 = 0; nt2 < 4; ++nt2)
#pragma unroll
      for (int r = 0; r < 4; ++r) {
        int m = m0 + wr * 64 + mt * 16 + g * 4 + r;
        int n = n0 + wc * 64 + nt2 * 16 + r16;
        Cf[(size_t)m * N + n] = acc[mt][nt2][r];
      }
}

// ---- causal flash attention v6 (R12-proven: 78.4 us) -----------------------
// QBLK=128 (4 waves x 32 q-cols), KVBLK=64, double-buffered K/V, XOR swizzle.
// 32x32x16 MFMA, swapped operands: S^T = mfma(K, Q). Softmax fully in-register;
// P redistributed to PV B-fragments via permlane32_swap (T12). exp2-domain,
// defer-max (T13). XCD-affinity: each XCD's co-resident blocks cover 8 heads
// (KV working set 4 MB = one L2), globally heavy-first.
// RETIRED after measurement: seeded accumulator (R5/R13: VGPR spill, 405 MB
// scratch), skewed qt map (R14: occupancy 33->23%), QBLK=256 (R15: 8-wave
// barrier variance + causal idle waves, 78->89 us). Do not re-attempt.
DEVI void stage_tile(const unsigned short* gbase, size_t rowstride,
                     unsigned short* lds, int tid) {
#pragma unroll
  for (int it = 0; it < 2; ++it) {
    int c = it * 256 + tid;
    int row = c >> 3, j = c & 7;
    int src = ((j * 16) ^ ((row & 7) << 4)) >> 1;  // shorts
    gll16(gbase + (size_t)row * rowstride + src, lds + c * 8);
  }
}

__global__ __launch_bounds__(256, 4) void attn_causal(
    const unsigned short* __restrict__ Q, const unsigned short* __restrict__ Kv,
    const unsigned short* __restrict__ VT, unsigned short* __restrict__ Y) {
  __shared__ unsigned short Ks[2][64 * 64];   // [t][d], swizzled
  __shared__ unsigned short Vs[2][64 * 64];   // [d][t], swizzled

  const int tid = threadIdx.x;
  const int lane = tid & 63;
  const int w = tid >> 6;
  const int l5 = lane & 31, h = lane >> 5;

  // XCD-affinity remap: xcd = lin&7 handles heads {xcd, xcd+8, ...};
  // qt descending -> all 64 heads' heaviest blocks dispatch first.
  const int lin = blockIdx.x + blockIdx.y * gridDim.x;  // 0..1023
  const int xcd = lin & 7;
  const int idx = lin >> 3;                 // 0..127
  const int qt = (ST / 128 - 1) - (idx >> 3);
  const int bh = xcd + 8 * (idx & 7);
  const size_t base = (size_t)bh * ST * SD;

  const int q_glob = qt * 128 + w * 32 + l5;   // this lane's q-row
  const int qwmin = qt * 128 + w * 32;         // wave q range [qwmin, qwmin+31]

  // Q B-fragments: col n = q = lane&31, k = h*8 + i, chained over kk (d-slices)
  bf16x8 qf[4];
#pragma unroll
  for (int kk = 0; kk < 4; ++kk)
    qf[kk] = ld8(Q + base + (size_t)q_glob * SD + kk * 16 + h * 8);

  float mrow = -__builtin_inff();
  float lrow = 0.f;
  f32x16 acc[2] = {};  // O^T: lane q=l5, d = dblk*32 + (reg&3) + 4h + 8*(reg>>2)

  const int nkv = 2 * qt + 2;
  stage_tile(Kv + base, SD, Ks[0], tid);
  stage_tile(VT + base, ST, Vs[0], tid);
  __syncthreads();

  for (int kvt = 0; kvt < nkv; ++kvt) {
    const int cur = kvt & 1;
    if (kvt + 1 < nkv) {  // prefetch next tile into other buffer
      stage_tile(Kv + base + (size_t)(kvt + 1) * 64 * SD, SD, Ks[cur ^ 1], tid);
      stage_tile(VT + base + (kvt + 1) * 64, ST, Vs[cur ^ 1], tid);
    }

    // tiles fully above this wave's q range contribute nothing
    const bool active = (kvt * 64) <= (qwmin + 31);
    if (active) {
      // S^T = K Q^T : two 32t x 32q blocks; lane owns q=l5, t-half per h
      f32x16 s0 = {}, s1 = {};
      __builtin_amdgcn_s_setprio(1);
#pragma unroll
      for (int kk = 0; kk < 4; ++kk) {
        bf16x8 k0 = ldswz(Ks[cur], l5, kk * 16 + h * 8);
        s0 = MFMA32(k0, qf[kk], s0);
      }
#pragma unroll
      for (int kk = 0; kk < 4; ++kk) {
        bf16x8 k1 = ldswz(Ks[cur], 32 + l5, kk * 16 + h * 8);
        s1 = MFMA32(k1, qf[kk], s1);
      }
      __builtin_amdgcn_s_setprio(0);

      if (kvt * 64 + 63 > qwmin) {  // diagonal overlap: causal mask
        const int t0 = kvt * 64 + 4 * h;
#pragma unroll
        for (int reg = 0; reg < 16; ++reg) {
          int t = t0 + (reg & 3) + 8 * (reg >> 2);
          if (t > q_glob) s0[reg] = -__builtin_inff();
          if (t + 32 > q_glob) s1[reg] = -__builtin_inff();
        }
      }

      // row max: elementwise + in-lane tree + one half-swap
      f32x16 mx;
#pragma unroll
      for (int i = 0; i < 16; ++i) mx[i] = fmaxf(s0[i], s1[i]);
#pragma unroll
      for (int i = 0; i < 8; ++i) mx[i] = fmaxf(mx[i], mx[i + 8]);
#pragma unroll
      for (int i = 0; i < 4; ++i) mx[i] = fmaxf(mx[i], mx[i + 4]);
      float bm = fmaxf(fmaxf(mx[0], mx[1]), fmaxf(mx[2], mx[3]));
      bm = swaphalf_max(bm);

      // defer-max: rescale only if running max grew by more than DMTHR
      if (__any(bm > mrow + DMTHR)) {
        float mn = fmaxf(mrow, bm);
        float corr = exp2f(mrow - mn);  // first tile: exp2(-inf)=0
        mrow = mn;
        lrow *= corr;
#pragma unroll
        for (int dblk = 0; dblk < 2; ++dblk)
#pragma unroll
          for (int i = 0; i < 16; ++i) acc[dblk][i] *= corr;
      }

      // P = exp2(S - m), in-lane sum + half-swap
#pragma unroll
      for (int i = 0; i < 16; ++i) {
        s0[i] = exp2f(s0[i] - mrow);
        s1[i] = exp2f(s1[i] - mrow);
      }
      f32x16 sm;
#pragma unroll
      for (int i = 0; i < 16; ++i) sm[i] = s0[i] + s1[i];
#pragma unroll
      for (int i = 0; i < 8; ++i) sm[i] += sm[i + 8];
#pragma unroll
      for (int i = 0; i < 4; ++i) sm[i] += sm[i + 4];
      float rs = (sm[0] + sm[1]) + (sm[2] + sm[3]);
      lrow += swaphalf_add(rs);

      // pack P -> bf16 PV B-fragments via permlane32_swap (no LDS roundtrip)
      bf16x8 pb[2][2];
      auto packblk = [&](const f32x16& S, bf16x8* out) {
        unsigned a = pkbf(S[0], S[1]), b2 = pkbf(S[2], S[3]);
        unsigned c = pkbf(S[4], S[5]), d2 = pkbf(S[6], S[7]);
        auto r0 = __builtin_amdgcn_permlane32_swap(a, c, false, false);
        auto r1 = __builtin_amdgcn_permlane32_swap(b2, d2, false, false);
        uint32x4v w0 = {(unsigned)r0[0], (unsigned)r1[0], (unsigned)r0[1], (unsigned)r1[1]};
        out[0] = __builtin_bit_cast(bf16x8, w0);
        unsigned e = pkbf(S[8], S[9]), f2 = pkbf(S[10], S[11]);
        unsigned g2 = pkbf(S[12], S[13]), h2 = pkbf(S[14], S[15]);
        auto r2 = __builtin_amdgcn_permlane32_swap(e, g2, false, false);
        auto r3 = __builtin_amdgcn_permlane32_swap(f2, h2, false, false);
        uint32x4v w1 = {(unsigned)r2[0], (unsigned)r3[0], (unsigned)r2[1], (unsigned)r3[1]};
        out[1] = __builtin_bit_cast(bf16x8, w1);
      };
      packblk(s0, pb[0]);
      packblk(s1, pb[1]);

      // O^T += V^T P^T : A = V^T (d rows), B = P^T (q cols)
      __builtin_amdgcn_s_setprio(1);
#pragma unroll
      for (int dblk = 0; dblk < 2; ++dblk)
#pragma unroll
        for (int tt = 0; tt < 2; ++tt)
#pragma unroll
          for (int sl = 0; sl < 2; ++sl) {
            bf16x8 va = ldswz(Vs[cur], dblk * 32 + l5, tt * 32 + sl * 16 + h * 8);
            acc[dblk] = MFMA32(va, pb[tt][sl], acc[dblk]);
          }
      __builtin_amdgcn_s_setprio(0);
    }

    __syncthreads();  // drains vmcnt (next tile staged) + guards buffer reuse
  }

  // epilogue: Y[B,T,E] bf16, e = head*64 + d; 4 consecutive d per reg-group
  const int b = bh >> 4, hd = bh & 15;
  const float inv = 1.f / lrow;
#pragma unroll
  for (int dblk = 0; dblk < 2; ++dblk)
#pragma unroll
    for (int rg = 0; rg < 4; ++rg) {
      bf16x4 o;
#pragma unroll
      for (int j = 0; j < 4; ++j) o[j] = (__bf16)(acc[dblk][rg * 4 + j] * inv);
      int d = dblk * 32 + rg * 8 + 4 * h;
      *(ushortx4*)&Y[((size_t)b * ST + q_glob) * SE + hd * SD + d] =
          __builtin_bit_cast(ushortx4, o);
    }
}

// ---- launch ----------------------------------------------------------------
extern "C" void kernel_launch(void* const* d_in, const int* in_sizes, int n_in,
                              void* d_out, int out_size, void* d_ws, size_t ws_size,
                              hipStream_t stream) {
  const float* x = (const float*)d_in[0];       // [4,2048,1024]
  const float* w_qkv = (const float*)d_in[1];   // [3072,1024]
  const float* w_out = (const float*)d_in[2];   // [1024,1024]
  float* out = (float*)d_out;                   // [4,2048,1024] f32

  const size_t NX = (size_t)SB * ST * SE;       // 8388608
  const size_t NQKV = (size_t)3 * SE * SE;      // 3145728
  const size_t NWO = (size_t)SE * SE;           // 1048576
  const size_t NHD = (size_t)SB * SH * ST * SD; // 8388608

  unsigned short* xb    = (unsigned short*)d_ws;        // 16MB, reused as Y later
  unsigned short* wqkvb = xb + NX;                      // 6MB
  unsigned short* woutb = wqkvb + NQKV;                 // 2MB
  unsigned short* q     = woutb + NWO;                  // 16MB
  unsigned short* k     = q + NHD;                      // 16MB
  unsigned short* vT    = k + NHD;                      // 16MB
  unsigned short* y     = xb;                           // alias (xb dead after GEMM1)

  const int ncvt = NXq4 + NQKVq4 + NWOq4;       // 3145728
  cvt_all<<<ncvt / 256, 256, 0, stream>>>(x, w_qkv, w_out, xb, wqkvb, woutb);

  // qkv = x @ w_qkv^T, scattered into Q/K/VT   (grid 12x32 = 384, %8==0)
  gemm_big<1><<<dim3(3 * SE / 256, SB * ST / 256), 512, 0, stream>>>(
      xb, wqkvb, nullptr, q, k, vT, SB * ST, 3 * SE, SE);

  attn_causal<<<dim3(ST / 128, SB * SH), 256, 0, stream>>>(q, k, vT, y);

  // out = y @ w_out^T (f32 out)   (R9-proven 128x128 kernel, 512 blocks)
  gemm_sm<<<dim3(SE / 128, SB * ST / 128), 256, 0, stream>>>(
      y, woutb, out, SB * ST, SE, SE);
}